// Round 13
// baseline (1673.915 us; speedup 1.0000x reference)
//
#include <hip/hip_runtime.h>
#include <math.h>

#define H 8
#define K 4
#define NN 4
#define D 256
#define NQ 1024
#define NKV 2048
#define BATCH 2
#define CH 32           // D / H
#define GC 16           // grid cells per axis
#define CELLH 0.0625f   // 1/16
#define NPTS 32768      // points per batch = H*NQ*K
#define LDSCAP 512      // staged-candidate capacity

// workspace layout (bytes)
#define OFF_LOC   0u          // 65536 * float2 = 512 KB
#define OFF_ATTN  524288u     // 65536 * f32    = 256 KB
#define OFF_VWS   786432u     // 16*2048*32 f32 = 4 MB
#define OFF_HEAD  4980736u    // 2*1024*256 f32 = 2 MB
#define OFF_PTS   7077888u    // 2*2048 float4  = 64 KB (cell-sorted)
#define OFF_CST   7143424u    // 2*257 i32 kv cell starts (pad 4K)
#define OFF_QCST  7147520u    // 2*257 i32 query cell starts (pad 4K)
#define OFF_QIDS  7151616u    // 65536 i32 = 256 KB
#define OFF_IDX   7413760u    // 65536 int4 = 1 MB
#define WS_NEED   8462336u

// ---------------------------------------------------------------------------
// Branchless lexicographic (d, idx) stable top-4 insert — f32/i32 only.
// Order-independent; reproduces lax.top_k (d asc, ties idx asc).
// ---------------------------------------------------------------------------
__device__ __forceinline__ void lexins(float t, int n,
                                       float& d0, float& d1, float& d2, float& d3,
                                       int& i0, int& i1, int& i2, int& i3) {
    bool c0 = (t < d0) || (t == d0 && n < i0);
    bool c1 = (t < d1) || (t == d1 && n < i1);
    bool c2 = (t < d2) || (t == d2 && n < i2);
    bool c3 = (t < d3) || (t == d3 && n < i3);
    d3 = c3 ? (c2 ? d2 : t) : d3;   i3 = c3 ? (c2 ? i2 : n) : i3;
    d2 = c2 ? (c1 ? d1 : t) : d2;   i2 = c2 ? (c1 ? i1 : n) : i2;
    d1 = c1 ? (c0 ? d0 : t) : d1;   i1 = c1 ? (c0 ? i0 : n) : i1;
    d0 = c0 ? t : d0;               i0 = c0 ? n : i0;
}

// dedup variant for merges/rescans whose feed may repeat existing entries
__device__ __forceinline__ void lexins_d(float t, int n,
                                         float& d0, float& d1, float& d2, float& d3,
                                         int& i0, int& i1, int& i2, int& i3) {
    bool nd = !((n == i0) | (n == i1) | (n == i2) | (n == i3));
    bool c0 = nd && ((t < d0) || (t == d0 && n < i0));
    bool c1 = nd && ((t < d1) || (t == d1 && n < i1));
    bool c2 = nd && ((t < d2) || (t == d2 && n < i2));
    bool c3 = nd && ((t < d3) || (t == d3 && n < i3));
    d3 = c3 ? (c2 ? d2 : t) : d3;   i3 = c3 ? (c2 ? i2 : n) : i3;
    d2 = c2 ? (c1 ? d1 : t) : d2;   i2 = c2 ? (c1 ? i1 : n) : i2;
    d1 = c1 ? (c0 ? d0 : t) : d1;   i1 = c1 ? (c0 ? i0 : n) : i1;
    d0 = c0 ? t : d0;               i0 = c0 ? n : i0;
}

// strict-< variant for the ascending-order brute-force fallback kernel
__device__ __forceinline__ void bins4(float t, int n,
                                      float& d0, float& d1, float& d2, float& d3,
                                      int& i0, int& i1, int& i2, int& i3) {
    bool c0 = t < d0, c1 = t < d1, c2 = t < d2, c3 = t < d3;
    d3 = c3 ? (c2 ? d2 : t) : d3;   i3 = c3 ? (c2 ? i2 : n) : i3;
    d2 = c2 ? (c1 ? d1 : t) : d2;   i2 = c2 ? (c1 ? i1 : n) : i2;
    d1 = c1 ? (c0 ? d0 : t) : d1;   i1 = c1 ? (c0 ? i0 : n) : i1;
    d0 = c0 ? t : d0;               i0 = c0 ? n : i0;
}

// ---------------------------------------------------------------------------
// Kernel 1 (FUSED): blocks [0, B*NQ): off/attn projections (fmaf chain =
// Eigen/oneDNN sgemm semantics, bias after).  Blocks [B*NQ, B*NQ+B): kv
// binning into 16x16 cells (cell-sorted float4(-2x,-2y,x^2+y^2,idx)).
// ---------------------------------------------------------------------------
__global__ void k_offattn_bin(const float* __restrict__ q, const float* __restrict__ qpos,
                              const float* __restrict__ Woff, const float* __restrict__ boff,
                              const float* __restrict__ Wattn, const float* __restrict__ battn,
                              const float* __restrict__ kvpos,
                              float* __restrict__ loc, float* __restrict__ attnw,
                              float4* __restrict__ pts4, int* __restrict__ cellStart) {
    #pragma clang fp contract(off)
    if (blockIdx.x >= BATCH * NQ) {
        int b = blockIdx.x - BATCH * NQ;
        int tid = threadIdx.x;
        __shared__ int cnt[GC * GC];
        __shared__ int ofs[GC * GC + 1];
        __shared__ int cur[GC * GC];
        for (int c = tid; c < GC * GC; c += 128) cnt[c] = 0;
        __syncthreads();
        for (int n = tid; n < NKV; n += 128) {
            float x = kvpos[(size_t)(b * NKV + n) * 2 + 0];
            float y = kvpos[(size_t)(b * NKV + n) * 2 + 1];
            int cix = min(GC - 1, max(0, (int)floorf(x * (float)GC)));
            int ciy = min(GC - 1, max(0, (int)floorf(y * (float)GC)));
            atomicAdd(&cnt[ciy * GC + cix], 1);
        }
        __syncthreads();
        if (tid == 0) {
            int s = 0;
            for (int c = 0; c < GC * GC; ++c) { ofs[c] = s; s += cnt[c]; }
            ofs[GC * GC] = s;
        }
        __syncthreads();
        for (int t = tid; t < GC * GC + 1; t += 128) cellStart[b * 257 + t] = ofs[t];
        for (int c = tid; c < GC * GC; c += 128) cur[c] = ofs[c];
        __syncthreads();
        for (int n = tid; n < NKV; n += 128) {
            float x = kvpos[(size_t)(b * NKV + n) * 2 + 0];
            float y = kvpos[(size_t)(b * NKV + n) * 2 + 1];
            int cix = min(GC - 1, max(0, (int)floorf(x * (float)GC)));
            int ciy = min(GC - 1, max(0, (int)floorf(y * (float)GC)));
            int pos = atomicAdd(&cur[ciy * GC + cix], 1);
            pts4[(size_t)b * NKV + pos] = make_float4(-2.0f * x, -2.0f * y, x * x + y * y, (float)n);
        }
        return;
    }
    int row = blockIdx.x;            // b*NQ + q
    int b = row >> 10, qi = row & (NQ - 1);
    __shared__ float qs[D];
    for (int d = threadIdx.x; d < D; d += blockDim.x) qs[d] = q[(size_t)row * D + d];
    __syncthreads();
    int j = threadIdx.x;
    if (j < 64) {
        float acc = 0.0f;
        for (int d = 0; d < D; ++d) acc = fmaf(qs[d], Woff[d * 64 + j], acc);
        float off = acc + boff[j];               // bias after, like np
        int xy = j & 1;
        int hk = j >> 1;                         // h*4 + k
        int h = hk >> 2, k = hk & 3;
        float L = qpos[(size_t)row * 2 + xy] + off;
        int g = ((b * H + h) * NQ + qi) * K + k;
        loc[(size_t)g * 2 + xy] = L;
    } else if (j < 96) {
        int j2 = j - 64;                         // h*4 + k
        float acc = 0.0f;
        for (int d = 0; d < D; ++d) acc = fmaf(qs[d], Wattn[d * 32 + j2], acc);
        acc += battn[j2];
        float m = acc;
        m = fmaxf(m, __shfl_xor(m, 1));
        m = fmaxf(m, __shfl_xor(m, 2));
        float e = expf(acc - m);
        float s = e;
        s += __shfl_xor(s, 1);
        s += __shfl_xor(s, 2);
        float w = e / s;
        int h = j2 >> 2, k = j2 & 3;
        attnw[((b * H + h) * NQ + qi) * K + k] = w;
    }
}

// ---------------------------------------------------------------------------
// Kernel Q: bin the 32768 sampling points (per batch) by clamped cell.
// Order within a cell is nondeterministic; downstream per-query result is
// order-invariant, so output is deterministic.
// ---------------------------------------------------------------------------
__global__ void k_qbin(const float* __restrict__ loc, int* __restrict__ qcst,
                       int* __restrict__ qids) {
    int b = blockIdx.x;
    int tid = threadIdx.x;
    __shared__ int cnt[GC * GC];
    __shared__ int ofs[GC * GC + 1];
    __shared__ int cur[GC * GC];
    cnt[tid] = 0;
    __syncthreads();
    const float2* lp = (const float2*)loc;
    for (int i = tid; i < NPTS; i += 256) {
        float2 L = lp[b * NPTS + i];
        int cx = min(GC - 1, max(0, (int)floorf(L.x * (float)GC)));
        int cy = min(GC - 1, max(0, (int)floorf(L.y * (float)GC)));
        atomicAdd(&cnt[cy * GC + cx], 1);
    }
    __syncthreads();
    if (tid == 0) {
        int s = 0;
        for (int c = 0; c < GC * GC; ++c) { ofs[c] = s; s += cnt[c]; }
        ofs[GC * GC] = s;
    }
    __syncthreads();
    qcst[b * 257 + tid] = ofs[tid];
    if (tid == 0) qcst[b * 257 + 256] = ofs[256];
    cur[tid] = ofs[tid];
    __syncthreads();
    for (int i = tid; i < NPTS; i += 256) {
        int g = b * NPTS + i;
        float2 L = lp[g];
        int cx = min(GC - 1, max(0, (int)floorf(L.x * (float)GC)));
        int cy = min(GC - 1, max(0, (int)floorf(L.y * (float)GC)));
        int pos = atomicAdd(&cur[cy * GC + cx], 1);
        qids[b * NPTS + pos] = g;
    }
}

// ---------------------------------------------------------------------------
// Kernel 2: values = kv @ W_v + b_v, stored transposed as [b*H][n_kv][32] f32.
// ---------------------------------------------------------------------------
__global__ void k_values(const float* __restrict__ kv, const float* __restrict__ Wv,
                         const float* __restrict__ bv, float* __restrict__ vws) {
    int r0 = blockIdx.x * 4;         // row = b*NKV + n
    __shared__ float ks[4][D];
    for (int t = threadIdx.x; t < 4 * D; t += 256) ks[t >> 8][t & 255] = kv[(size_t)r0 * D + t];
    __syncthreads();
    int c = threadIdx.x;             // h*32 + cc
    float a0 = 0.f, a1 = 0.f, a2 = 0.f, a3 = 0.f;
    for (int d = 0; d < D; ++d) {
        float w = Wv[d * D + c];
        a0 = fmaf(ks[0][d], w, a0); a1 = fmaf(ks[1][d], w, a1);
        a2 = fmaf(ks[2][d], w, a2); a3 = fmaf(ks[3][d], w, a3);
    }
    float bias = bv[c];
    a0 += bias; a1 += bias; a2 += bias; a3 += bias;
    int h = c >> 5, cc = c & 31;
    float va[4] = {a0, a1, a2, a3};
    for (int r = 0; r < 4; ++r) {
        int row = r0 + r;
        int b = row >> 11, n = row & (NKV - 1);
        vws[(((size_t)(b * H + h) * NKV) + n) * CH + cc] = va[r];
    }
}

// ---------------------------------------------------------------------------
// Kernel 3a (TILED SCAN): one 64-thread block per (batch, cell, sub 0..3).
// Stage the cell's clamped 5x5 kv-neighborhood into LDS once (block-uniform
// bounds); every query of the cell scans the SAME flat LDS range (broadcast
// reads, no conflicts), 2 lanes/query 4-wide.  Bound to unscanned region
// >= 2 cells for interior cells -> fallback (dedup full scan) ~never fires.
// t formula bitwise-identical; lex selection is order/set-invariant.
// ---------------------------------------------------------------------------
__global__ void k_scan_tiled(const float* __restrict__ loc,
                             const float4* __restrict__ pts4,
                             const int* __restrict__ cellStart,
                             const int* __restrict__ qcst, const int* __restrict__ qids,
                             int4* __restrict__ idxb) {
    #pragma clang fp contract(off)
    int blk = blockIdx.x;
    int sub  = blk & 3;
    int cell = (blk >> 2) & (GC * GC - 1);
    int b    = blk >> 10;
    int cx = cell & (GC - 1), cy = cell >> 4;
    int x0 = max(cx - 2, 0), x1 = min(cx + 2, GC - 1);
    int y0 = max(cy - 2, 0), y1 = min(cy + 2, GC - 1);

    const float4* gp = pts4 + (size_t)b * NKV;
    const int* cs = cellStart + b * 257;

    __shared__ float4 lpts[LDSCAP];
    int m = 0;
    for (int ry = y0; ry <= y1; ++ry) {
        int a = cs[ry * GC + x0];
        int e = cs[ry * GC + x1 + 1];
        int len = e - a;
        if (m + len <= LDSCAP)
            for (int i = threadIdx.x; i < len; i += 64) lpts[m + i] = gp[a + i];
        m += len;
    }
    bool ovf = (m > LDSCAP);
    __syncthreads();

    int qbase = qcst[b * 257 + cell];
    int qcnt  = qcst[b * 257 + cell + 1] - qbase;
    int s = threadIdx.x & 1;

    for (int slot = (threadIdx.x >> 1); 4 * slot + sub < qcnt; slot += 32) {
        int qs = 4 * slot + sub;
        int qid = qids[b * NPTS + qbase + qs];
        float2 L = ((const float2*)loc)[qid];
        float lx = L.x, ly = L.y;
        float sl = lx * lx + ly * ly;

        float d0 = 1e30f, d1 = 1e30f, d2 = 1e30f, d3 = 1e30f;
        int i0 = 0x7FFFFFFF, i1 = 0x7FFFFFFF, i2 = 0x7FFFFFFF, i3 = 0x7FFFFFFF;

#define INS1(P) { float tt = (sl + (P).z) + fmaf(ly, (P).y, lx * (P).x);       \
                  lexins(tt, (int)(P).w, d0, d1, d2, d3, i0, i1, i2, i3); }

        if (!ovf) {
            int nfull = m & ~7;
            for (int f = s * 4; f < nfull; f += 8) {
                float4 c0 = lpts[f], c1 = lpts[f + 1], c2 = lpts[f + 2], c3 = lpts[f + 3];
                INS1(c0); INS1(c1); INS1(c2); INS1(c3);
            }
            for (int f = nfull + s; f < m; f += 2) { float4 cc = lpts[f]; INS1(cc); }
        }
#undef INS1

#define MERGE1 { float e0 = __shfl_xor(d0, 1), e1 = __shfl_xor(d1, 1);         \
                 float e2 = __shfl_xor(d2, 1), e3 = __shfl_xor(d3, 1);         \
                 int j0 = __shfl_xor(i0, 1), j1 = __shfl_xor(i1, 1);           \
                 int j2 = __shfl_xor(i2, 1), j3 = __shfl_xor(i3, 1);           \
                 lexins_d(e0, j0, d0, d1, d2, d3, i0, i1, i2, i3);             \
                 lexins_d(e1, j1, d0, d1, d2, d3, i0, i1, i2, i3);             \
                 lexins_d(e2, j2, d0, d1, d2, d3, i0, i1, i2, i3);             \
                 lexins_d(e3, j3, d0, d1, d2, d3, i0, i1, i2, i3); }

        MERGE1;

        float bound = 1e30f;
        if (x0 > 0)      bound = fminf(bound, lx - (float)x0 * CELLH);
        if (x1 < GC - 1) bound = fminf(bound, (float)(x1 + 1) * CELLH - lx);
        if (y0 > 0)      bound = fminf(bound, ly - (float)y0 * CELLH);
        if (y1 < GC - 1) bound = fminf(bound, (float)(y1 + 1) * CELLH - ly);
        bool done = !ovf && (d3 < bound * bound - 1e-5f);
        if (!done) {
            for (int jj = s; jj < NKV; jj += 2) {
                float4 cc = gp[jj];
                float tt = (sl + cc.z) + fmaf(ly, cc.y, lx * cc.x);
                lexins_d(tt, (int)cc.w, d0, d1, d2, d3, i0, i1, i2, i3);
            }
            MERGE1;
        }
#undef MERGE1
        if (s == 0) idxb[qid] = make_int4(i0, i1, i2, i3);
    }
}

// ---------------------------------------------------------------------------
// Kernel 3b (TAIL): Shepard weights + value gather + k-reduce + head write.
// 8 lanes per point; lane s handles channel chunk s; k-sum via shfl 8/16.
// ---------------------------------------------------------------------------
__global__ void k_tail(const float* __restrict__ kvpos, const float* __restrict__ loc,
                       const float* __restrict__ attnw, const float* __restrict__ vws,
                       const float* __restrict__ sp, const int4* __restrict__ idxb,
                       float* __restrict__ head) {
    #pragma clang fp contract(off)
    int lane = threadIdx.x;
    int s = lane & 7;
    int g = blockIdx.x * 32 + (lane >> 3);
    int bh = g >> 12;
    int bb = bh >> 3, h = bh & 7;
    int qi = (g >> 2) & (NQ - 1);

    int4 I = idxb[g];
    float2 L = ((const float2*)loc)[g];
    float lx = L.x, ly = L.y;
    float power = fmaxf(sp[0], 0.0f) + 1e-6f;

    int idx[4] = {I.x, I.y, I.z, I.w};
    float z[4];
    #pragma unroll
    for (int u = 0; u < 4; ++u) {
        float kx = kvpos[(size_t)(bb * NKV + idx[u]) * 2 + 0];
        float ky = kvpos[(size_t)(bb * NKV + idx[u]) * 2 + 1];
        float dx = kx - lx;
        float dy = ky - ly;
        float dist = sqrtf(dx * dx + dy * dy) + 1e-6f;
        z[u] = -power * dist;
    }
    float mz = fmaxf(fmaxf(z[0], z[1]), fmaxf(z[2], z[3]));
    float e0 = expf(z[0] - mz), e1 = expf(z[1] - mz), e2 = expf(z[2] - mz), e3 = expf(z[3] - mz);
    float esum = e0 + e1 + e2 + e3;
    float w0 = e0 / esum, w1 = e1 / esum, w2 = e2 / esum, w3 = e3 / esum;

    const float4* vp0 = (const float4*)(vws + ((size_t)bh * NKV + I.x) * CH);
    const float4* vp1 = (const float4*)(vws + ((size_t)bh * NKV + I.y) * CH);
    const float4* vp2 = (const float4*)(vws + ((size_t)bh * NKV + I.z) * CH);
    const float4* vp3 = (const float4*)(vws + ((size_t)bh * NKV + I.w) * CH);
    float a = attnw[g];
    float4* hp = (float4*)(head + ((size_t)(bb * NQ + qi)) * D + h * CH);
    float4 x0 = vp0[s], x1 = vp1[s], x2 = vp2[s], x3 = vp3[s];
    float4 rr;
    rr.x = a * (w0 * x0.x + w1 * x1.x + w2 * x2.x + w3 * x3.x);
    rr.y = a * (w0 * x0.y + w1 * x1.y + w2 * x2.y + w3 * x3.y);
    rr.z = a * (w0 * x0.z + w1 * x1.z + w2 * x2.z + w3 * x3.z);
    rr.w = a * (w0 * x0.w + w1 * x1.w + w2 * x2.w + w3 * x3.w);
    rr.x += __shfl_xor(rr.x, 8); rr.x += __shfl_xor(rr.x, 16);   // sum over k
    rr.y += __shfl_xor(rr.y, 8); rr.y += __shfl_xor(rr.y, 16);
    rr.z += __shfl_xor(rr.z, 8); rr.z += __shfl_xor(rr.z, 16);
    rr.w += __shfl_xor(rr.w, 8); rr.w += __shfl_xor(rr.w, 16);
    if (((lane >> 3) & 3) == 0) hp[s] = rr;                      // k==0 lanes write
}

// Fallback (ws too small): brute-force fused scan (round-4 validated path)
__global__ void k_knn_fused(const float* __restrict__ kvpos, const float* __restrict__ loc,
                            const float* __restrict__ attnw, const float* __restrict__ vws,
                            const float* __restrict__ sp, float* __restrict__ head) {
    #pragma clang fp contract(off)
    int g = blockIdx.x * 256 + threadIdx.x;
    int bh = g >> 12;
    int b = bh >> 3;
    __shared__ float sx[NKV];
    __shared__ float sy[NKV];
    __shared__ float sz[NKV];
    for (int n = threadIdx.x; n < NKV; n += 256) {
        float x = kvpos[(size_t)(b * NKV + n) * 2 + 0];
        float y = kvpos[(size_t)(b * NKV + n) * 2 + 1];
        sx[n] = -2.0f * x;
        sy[n] = -2.0f * y;
        sz[n] = x * x + y * y;
    }
    __syncthreads();
    float2 L = ((const float2*)loc)[g];
    float lx = L.x, ly = L.y;
    float sl = lx * lx + ly * ly;
    const float4* x4 = (const float4*)sx;
    const float4* y4 = (const float4*)sy;
    const float4* z4 = (const float4*)sz;
    float d0 = 1e30f, d1 = 1e30f, d2 = 1e30f, d3 = 1e30f;
    int i0 = 0, i1 = 0, i2 = 0, i3 = 0;
    for (int n = 0; n < NKV; n += 4) {
        int v = n >> 2;
        float4 xA = x4[v], yA = y4[v], zA = z4[v];
        float t0 = (sl + zA.x) + fmaf(ly, yA.x, lx * xA.x);
        float t1 = (sl + zA.y) + fmaf(ly, yA.y, lx * xA.y);
        float t2 = (sl + zA.z) + fmaf(ly, yA.z, lx * xA.z);
        float t3 = (sl + zA.w) + fmaf(ly, yA.w, lx * xA.w);
        bins4(t0, n + 0, d0, d1, d2, d3, i0, i1, i2, i3);
        bins4(t1, n + 1, d0, d1, d2, d3, i0, i1, i2, i3);
        bins4(t2, n + 2, d0, d1, d2, d3, i0, i1, i2, i3);
        bins4(t3, n + 3, d0, d1, d2, d3, i0, i1, i2, i3);
    }
    float power = fmaxf(sp[0], 0.0f) + 1e-6f;
    int h = bh & 7;
    int qi = (g >> 2) & (NQ - 1);
    int k = g & 3;
    int idx[4] = {i0, i1, i2, i3};
    float z[4];
    #pragma unroll
    for (int u = 0; u < 4; ++u) {
        float kx = kvpos[(size_t)(b * NKV + idx[u]) * 2 + 0];
        float ky = kvpos[(size_t)(b * NKV + idx[u]) * 2 + 1];
        float dx = kx - lx;
        float dy = ky - ly;
        float dist = sqrtf(dx * dx + dy * dy) + 1e-6f;
        z[u] = -power * dist;
    }
    float m = fmaxf(fmaxf(z[0], z[1]), fmaxf(z[2], z[3]));
    float e0 = expf(z[0] - m), e1 = expf(z[1] - m), e2 = expf(z[2] - m), e3 = expf(z[3] - m);
    float esum = e0 + e1 + e2 + e3;
    float w0 = e0 / esum, w1 = e1 / esum, w2 = e2 / esum, w3 = e3 / esum;
    const float4* vp0 = (const float4*)(vws + ((size_t)bh * NKV + i0) * CH);
    const float4* vp1 = (const float4*)(vws + ((size_t)bh * NKV + i1) * CH);
    const float4* vp2 = (const float4*)(vws + ((size_t)bh * NKV + i2) * CH);
    const float4* vp3 = (const float4*)(vws + ((size_t)bh * NKV + i3) * CH);
    float a = attnw[g];
    float4 acc[8];
    #pragma unroll
    for (int t = 0; t < 8; ++t) {
        float4 x0 = vp0[t], x1 = vp1[t], x2 = vp2[t], x3 = vp3[t];
        float4 r;
        r.x = a * (w0 * x0.x + w1 * x1.x + w2 * x2.x + w3 * x3.x);
        r.y = a * (w0 * x0.y + w1 * x1.y + w2 * x2.y + w3 * x3.y);
        r.z = a * (w0 * x0.z + w1 * x1.z + w2 * x2.z + w3 * x3.z);
        r.w = a * (w0 * x0.w + w1 * x1.w + w2 * x2.w + w3 * x3.w);
        r.x += __shfl_xor(r.x, 1); r.x += __shfl_xor(r.x, 2);
        r.y += __shfl_xor(r.y, 1); r.y += __shfl_xor(r.y, 2);
        r.z += __shfl_xor(r.z, 1); r.z += __shfl_xor(r.z, 2);
        r.w += __shfl_xor(r.w, 1); r.w += __shfl_xor(r.w, 2);
        acc[t] = r;
    }
    float4* hp = (float4*)(head + ((size_t)(b * NQ + qi)) * D + h * CH);
    hp[k * 2]     = acc[k * 2];
    hp[k * 2 + 1] = acc[k * 2 + 1];
}

// ---------------------------------------------------------------------------
// Kernel 4: out = head @ W_out + b_out  (f32 store)
// ---------------------------------------------------------------------------
__global__ void k_out(const float* __restrict__ head, const float* __restrict__ Wout,
                      const float* __restrict__ bout, float* __restrict__ out) {
    int r0 = blockIdx.x * 4;
    __shared__ float hs[4][D];
    for (int t = threadIdx.x; t < 4 * D; t += 256) hs[t >> 8][t & 255] = head[(size_t)r0 * D + t];
    __syncthreads();
    int c = threadIdx.x;
    float a0 = 0.f, a1 = 0.f, a2 = 0.f, a3 = 0.f;
    for (int d = 0; d < D; ++d) {
        float w = Wout[d * D + c];
        a0 = fmaf(hs[0][d], w, a0); a1 = fmaf(hs[1][d], w, a1);
        a2 = fmaf(hs[2][d], w, a2); a3 = fmaf(hs[3][d], w, a3);
    }
    float bias = bout[c];
    out[(size_t)(r0 + 0) * D + c] = a0 + bias;
    out[(size_t)(r0 + 1) * D + c] = a1 + bias;
    out[(size_t)(r0 + 2) * D + c] = a2 + bias;
    out[(size_t)(r0 + 3) * D + c] = a3 + bias;
}

// ---------------------------------------------------------------------------
extern "C" void kernel_launch(void* const* d_in, const int* in_sizes, int n_in,
                              void* d_out, int out_size, void* d_ws, size_t ws_size,
                              hipStream_t stream) {
    (void)in_sizes; (void)n_in; (void)out_size;
    const float* q     = (const float*)d_in[0];
    const float* qpos  = (const float*)d_in[1];
    const float* kv    = (const float*)d_in[2];
    const float* kvp   = (const float*)d_in[3];
    const float* Woff  = (const float*)d_in[4];
    const float* boff  = (const float*)d_in[5];
    const float* Wattn = (const float*)d_in[6];
    const float* battn = (const float*)d_in[7];
    const float* Wv    = (const float*)d_in[8];
    const float* bv    = (const float*)d_in[9];
    const float* Wout  = (const float*)d_in[10];
    const float* bout  = (const float*)d_in[11];
    const float* sp    = (const float*)d_in[12];
    float* out = (float*)d_out;

    char* ws = (char*)d_ws;
    float* loc      = (float*)(ws + OFF_LOC);
    float* attnw    = (float*)(ws + OFF_ATTN);
    float* vws      = (float*)(ws + OFF_VWS);
    float* head     = (float*)(ws + OFF_HEAD);
    float4* pts4    = (float4*)(ws + OFF_PTS);
    int* cellStart  = (int*)(ws + OFF_CST);
    int* qcst       = (int*)(ws + OFF_QCST);
    int* qids       = (int*)(ws + OFF_QIDS);
    int4* idxb      = (int4*)(ws + OFF_IDX);

    bool grid_ok = ws_size >= (size_t)WS_NEED;
    int nblk = BATCH * NQ + (grid_ok ? BATCH : 0);
    hipLaunchKernelGGL(k_offattn_bin, dim3(nblk), dim3(128), 0, stream,
                       q, qpos, Woff, boff, Wattn, battn, kvp, loc, attnw, pts4, cellStart);
    hipLaunchKernelGGL(k_values, dim3(BATCH * NKV / 4), dim3(256), 0, stream,
                       kv, Wv, bv, vws);
    if (grid_ok) {
        hipLaunchKernelGGL(k_qbin, dim3(BATCH), dim3(256), 0, stream,
                           loc, qcst, qids);
        hipLaunchKernelGGL(k_scan_tiled, dim3(BATCH * GC * GC * 4), dim3(64), 0, stream,
                           loc, pts4, cellStart, qcst, qids, idxb);
        hipLaunchKernelGGL(k_tail, dim3(BATCH * H * NQ * K / 32), dim3(256), 0, stream,
                           kvp, loc, attnw, vws, sp, idxb, head);
    } else {
        hipLaunchKernelGGL(k_knn_fused, dim3(BATCH * H * NQ * K / 256), dim3(256), 0, stream,
                           kvp, loc, attnw, vws, sp, head);
    }
    hipLaunchKernelGGL(k_out, dim3(BATCH * NQ / 4), dim3(256), 0, stream,
                       head, Wout, bout, out);
}

// Round 14
// 138.401 us; speedup vs baseline: 12.0947x; 12.0947x over previous
//
#include <hip/hip_runtime.h>
#include <math.h>

#define H 8
#define K 4
#define NN 4
#define D 256
#define NQ 1024
#define NKV 2048
#define BATCH 2
#define CH 32           // D / H
#define GC 16           // grid cells per axis
#define CELLH 0.0625f   // 1/16

// workspace layout (bytes)
#define OFF_LOC   0u          // 65536 * float2 = 512 KB
#define OFF_ATTN  524288u     // 65536 * f32    = 256 KB
#define OFF_VWS   786432u     // 16*2048*32 f32 = 4 MB
#define OFF_HEAD  4980736u    // 2*1024*256 f32 = 2 MB
#define OFF_PTS   7077888u    // 2*2048 float4  = 64 KB (cell-sorted)
#define OFF_CST   7143424u    // 2*257 i32 cell starts (+pad)
#define WS_NEED   7147520u

// ---------------------------------------------------------------------------
// Branchless lexicographic (d, idx) stable top-4 insert — f32/i32 only.
// Order-independent; reproduces lax.top_k (d asc, ties idx asc).
// ---------------------------------------------------------------------------
__device__ __forceinline__ void lexins(float t, int n,
                                       float& d0, float& d1, float& d2, float& d3,
                                       int& i0, int& i1, int& i2, int& i3) {
    bool c0 = (t < d0) || (t == d0 && n < i0);
    bool c1 = (t < d1) || (t == d1 && n < i1);
    bool c2 = (t < d2) || (t == d2 && n < i2);
    bool c3 = (t < d3) || (t == d3 && n < i3);
    d3 = c3 ? (c2 ? d2 : t) : d3;   i3 = c3 ? (c2 ? i2 : n) : i3;
    d2 = c2 ? (c1 ? d1 : t) : d2;   i2 = c2 ? (c1 ? i1 : n) : i2;
    d1 = c1 ? (c0 ? d0 : t) : d1;   i1 = c1 ? (c0 ? i0 : n) : i1;
    d0 = c0 ? t : d0;               i0 = c0 ? n : i0;
}

// DEDUP variant: for ring re-merges where lists share phase-1 survivors.
__device__ __forceinline__ void lexins_d(float t, int n,
                                         float& d0, float& d1, float& d2, float& d3,
                                         int& i0, int& i1, int& i2, int& i3) {
    bool nd = !((n == i0) | (n == i1) | (n == i2) | (n == i3));
    bool c0 = nd && ((t < d0) || (t == d0 && n < i0));
    bool c1 = nd && ((t < d1) || (t == d1 && n < i1));
    bool c2 = nd && ((t < d2) || (t == d2 && n < i2));
    bool c3 = nd && ((t < d3) || (t == d3 && n < i3));
    d3 = c3 ? (c2 ? d2 : t) : d3;   i3 = c3 ? (c2 ? i2 : n) : i3;
    d2 = c2 ? (c1 ? d1 : t) : d2;   i2 = c2 ? (c1 ? i1 : n) : i2;
    d1 = c1 ? (c0 ? d0 : t) : d1;   i1 = c1 ? (c0 ? i0 : n) : i1;
    d0 = c0 ? t : d0;               i0 = c0 ? n : i0;
}

// strict-< variant for the ascending-order brute-force fallback
__device__ __forceinline__ void bins4(float t, int n,
                                      float& d0, float& d1, float& d2, float& d3,
                                      int& i0, int& i1, int& i2, int& i3) {
    bool c0 = t < d0, c1 = t < d1, c2 = t < d2, c3 = t < d3;
    d3 = c3 ? (c2 ? d2 : t) : d3;   i3 = c3 ? (c2 ? i2 : n) : i3;
    d2 = c2 ? (c1 ? d1 : t) : d2;   i2 = c2 ? (c1 ? i1 : n) : i2;
    d1 = c1 ? (c0 ? d0 : t) : d1;   i1 = c1 ? (c0 ? i0 : n) : i1;
    d0 = c0 ? t : d0;               i0 = c0 ? n : i0;
}

// ---------------------------------------------------------------------------
// Kernel 1 (FUSED): blocks [0, 256): off/attn projections, 8 query rows per
// block — one weight load feeds 8 fmaf chains (8x less weight traffic).
// Per-(row,output) fmaf chain is BITWISE-identical to the validated version
// (sequential d, bias after = Eigen/oneDNN sgemm semantics).
// Blocks [256, 256+B): kv binning into 16x16 cells.
// ---------------------------------------------------------------------------
__global__ void k_offattn_bin(const float* __restrict__ q, const float* __restrict__ qpos,
                              const float* __restrict__ Woff, const float* __restrict__ boff,
                              const float* __restrict__ Wattn, const float* __restrict__ battn,
                              const float* __restrict__ kvpos,
                              float* __restrict__ loc, float* __restrict__ attnw,
                              float4* __restrict__ pts4, int* __restrict__ cellStart) {
    #pragma clang fp contract(off)
    if (blockIdx.x >= (BATCH * NQ) / 8) {
        // ---- bin path (one block per batch, 128 threads) ----
        int b = blockIdx.x - (BATCH * NQ) / 8;
        int tid = threadIdx.x;
        __shared__ int cnt[GC * GC];
        __shared__ int ofs[GC * GC + 1];
        __shared__ int cur[GC * GC];
        for (int c = tid; c < GC * GC; c += 128) cnt[c] = 0;
        __syncthreads();
        for (int n = tid; n < NKV; n += 128) {
            float x = kvpos[(size_t)(b * NKV + n) * 2 + 0];
            float y = kvpos[(size_t)(b * NKV + n) * 2 + 1];
            int cix = min(GC - 1, max(0, (int)floorf(x * (float)GC)));
            int ciy = min(GC - 1, max(0, (int)floorf(y * (float)GC)));
            atomicAdd(&cnt[ciy * GC + cix], 1);
        }
        __syncthreads();
        if (tid == 0) {
            int s = 0;
            for (int c = 0; c < GC * GC; ++c) { ofs[c] = s; s += cnt[c]; }
            ofs[GC * GC] = s;
        }
        __syncthreads();
        for (int t = tid; t < GC * GC + 1; t += 128) cellStart[b * 257 + t] = ofs[t];
        for (int c = tid; c < GC * GC; c += 128) cur[c] = ofs[c];
        __syncthreads();
        for (int n = tid; n < NKV; n += 128) {
            float x = kvpos[(size_t)(b * NKV + n) * 2 + 0];
            float y = kvpos[(size_t)(b * NKV + n) * 2 + 1];
            int cix = min(GC - 1, max(0, (int)floorf(x * (float)GC)));
            int ciy = min(GC - 1, max(0, (int)floorf(y * (float)GC)));
            int pos = atomicAdd(&cur[ciy * GC + cix], 1);
            pts4[(size_t)b * NKV + pos] = make_float4(-2.0f * x, -2.0f * y, x * x + y * y, (float)n);
        }
        return;
    }
    // ---- offattn path: 8 rows per block ----
    int r0 = blockIdx.x * 8;
    __shared__ float qs[8][D];
    for (int t = threadIdx.x; t < 8 * D; t += 128) qs[t >> 8][t & 255] = q[(size_t)r0 * D + t];
    __syncthreads();
    int j = threadIdx.x;
    if (j < 64) {
        float acc[8];
        #pragma unroll
        for (int r = 0; r < 8; ++r) acc[r] = 0.0f;
        for (int d = 0; d < D; ++d) {
            float w = Woff[d * 64 + j];
            #pragma unroll
            for (int r = 0; r < 8; ++r) acc[r] = fmaf(qs[r][d], w, acc[r]);
        }
        float bo = boff[j];
        int xy = j & 1;
        int hk = j >> 1;                         // h*4 + k
        int h = hk >> 2, k = hk & 3;
        #pragma unroll
        for (int r = 0; r < 8; ++r) {
            int row = r0 + r;
            int b = row >> 10, qi = row & (NQ - 1);
            float L = qpos[(size_t)row * 2 + xy] + (acc[r] + bo);
            int g = ((b * H + h) * NQ + qi) * K + k;
            loc[(size_t)g * 2 + xy] = L;
        }
    } else if (j < 96) {
        int j2 = j - 64;                         // h*4 + k
        float acc[8];
        #pragma unroll
        for (int r = 0; r < 8; ++r) acc[r] = 0.0f;
        for (int d = 0; d < D; ++d) {
            float w = Wattn[d * 32 + j2];
            #pragma unroll
            for (int r = 0; r < 8; ++r) acc[r] = fmaf(qs[r][d], w, acc[r]);
        }
        float ba = battn[j2];
        int h = j2 >> 2, k = j2 & 3;
        #pragma unroll
        for (int r = 0; r < 8; ++r) {
            int row = r0 + r;
            int b = row >> 10, qi = row & (NQ - 1);
            float a = acc[r] + ba;
            float m = a;
            m = fmaxf(m, __shfl_xor(m, 1));
            m = fmaxf(m, __shfl_xor(m, 2));
            float e = expf(a - m);
            float s = e;
            s += __shfl_xor(s, 1);
            s += __shfl_xor(s, 2);
            attnw[((b * H + h) * NQ + qi) * K + k] = e / s;
        }
    }
}

// ---------------------------------------------------------------------------
// Kernel 2: values = kv @ W_v + b_v -> [b*H][n_kv][32] f32.  16 rows/block,
// 4x4 register tile per thread, float4 weight loads (4x less W traffic).
// ---------------------------------------------------------------------------
__global__ void k_values(const float* __restrict__ kv, const float* __restrict__ Wv,
                         const float* __restrict__ bv, float* __restrict__ vws) {
    int r0 = blockIdx.x * 16;        // row = b*NKV + n
    __shared__ float ks[16][D];      // 16 KB
    for (int t = threadIdx.x; t < 16 * D; t += 256) ks[t >> 8][t & 255] = kv[(size_t)r0 * D + t];
    __syncthreads();
    int cg = threadIdx.x & 63;       // col group: cols 4cg..4cg+3
    int rg = threadIdx.x >> 6;       // row group: rows 4rg..4rg+3
    float4 a0 = {0,0,0,0}, a1 = {0,0,0,0}, a2 = {0,0,0,0}, a3 = {0,0,0,0};
    for (int d = 0; d < D; ++d) {
        float4 w = *(const float4*)&Wv[d * D + cg * 4];
        float k0 = ks[rg * 4 + 0][d], k1 = ks[rg * 4 + 1][d];
        float k2 = ks[rg * 4 + 2][d], k3 = ks[rg * 4 + 3][d];
        a0.x = fmaf(k0, w.x, a0.x); a0.y = fmaf(k0, w.y, a0.y); a0.z = fmaf(k0, w.z, a0.z); a0.w = fmaf(k0, w.w, a0.w);
        a1.x = fmaf(k1, w.x, a1.x); a1.y = fmaf(k1, w.y, a1.y); a1.z = fmaf(k1, w.z, a1.z); a1.w = fmaf(k1, w.w, a1.w);
        a2.x = fmaf(k2, w.x, a2.x); a2.y = fmaf(k2, w.y, a2.y); a2.z = fmaf(k2, w.z, a2.z); a2.w = fmaf(k2, w.w, a2.w);
        a3.x = fmaf(k3, w.x, a3.x); a3.y = fmaf(k3, w.y, a3.y); a3.z = fmaf(k3, w.z, a3.z); a3.w = fmaf(k3, w.w, a3.w);
    }
    float4 bias = *(const float4*)&bv[cg * 4];
    int c = cg * 4, h = c >> 5, cc = c & 31;
    float4 va[4] = {a0, a1, a2, a3};
    #pragma unroll
    for (int rr = 0; rr < 4; ++rr) {
        int row = r0 + rg * 4 + rr;
        int b = row >> 11, n = row & (NKV - 1);
        float4 v;
        v.x = va[rr].x + bias.x; v.y = va[rr].y + bias.y;
        v.z = va[rr].z + bias.z; v.w = va[rr].w + bias.w;
        *(float4*)&vws[(((size_t)(b * H + h) * NKV) + n) * CH + cc] = v;
    }
}

// ---------------------------------------------------------------------------
// Kernel 3 (R9-validated, 66.9us): grid 4-NN, 8 lanes/point, 3x3 box + ring,
// flattened rows + 4-wide batched loads, inline tail.
// ---------------------------------------------------------------------------
__global__ void k_knn_grid2(const float* __restrict__ kvpos, const float* __restrict__ loc,
                            const float* __restrict__ attnw, const float* __restrict__ vws,
                            const float* __restrict__ sp,
                            const float4* __restrict__ pts4, const int* __restrict__ cellStart,
                            float* __restrict__ head) {
    #pragma clang fp contract(off)
    int lane = threadIdx.x;
    int s = lane & 7;
    int g = blockIdx.x * 32 + (lane >> 3);    // point id
    int b = g >> 15;
    int bh = g >> 12;

    __shared__ int cst[GC * GC + 1];
    for (int i = threadIdx.x; i < GC * GC + 1; i += 256) cst[i] = cellStart[b * 257 + i];
    __syncthreads();

    const float4* gp = pts4 + (size_t)b * NKV;
    float2 L = ((const float2*)loc)[g];
    float lx = L.x, ly = L.y;
    float sl = lx * lx + ly * ly;

    int ix = min(GC - 1, max(0, (int)floorf(lx * (float)GC)));
    int iy = min(GC - 1, max(0, (int)floorf(ly * (float)GC)));

    float d0 = 1e30f, d1 = 1e30f, d2 = 1e30f, d3 = 1e30f;
    int i0 = 0x7FFFFFFF, i1 = 0x7FFFFFFF, i2 = 0x7FFFFFFF, i3 = 0x7FFFFFFF;

#define INS1(P) { float tt = (sl + (P).z) + fmaf(ly, (P).y, lx * (P).x);      \
                  lexins(tt, (int)(P).w, d0, d1, d2, d3, i0, i1, i2, i3); }

    // ---- phase 1: clamped 3x3 box, flattened rows, 4-wide batched loads ----
    {
        int bx0 = max(ix - 1, 0), bx1 = min(ix + 1, GC - 1);
        int by0 = max(iy - 1, 0), by1 = min(iy + 1, GC - 1);
        int a0 = cst[by0 * GC + bx0];
        int l0 = cst[by0 * GC + bx1 + 1] - a0;
        int a1 = 0, l1 = 0, a2 = 0, l2 = 0;
        if (by0 + 1 <= by1) { a1 = cst[(by0 + 1) * GC + bx0]; l1 = cst[(by0 + 1) * GC + bx1 + 1] - a1; }
        if (by0 + 2 <= by1) { a2 = cst[(by0 + 2) * GC + bx0]; l2 = cst[(by0 + 2) * GC + bx1 + 1] - a2; }
        int l01 = l0 + l1;
        int m = l01 + l2;
        int f = s;
        for (; f + 24 < m; f += 32) {
            int f0 = f, f1 = f + 8, f2 = f + 16, f3 = f + 24;
            int j0 = f0 < l0 ? a0 + f0 : (f0 < l01 ? a1 + (f0 - l0) : a2 + (f0 - l01));
            int j1 = f1 < l0 ? a0 + f1 : (f1 < l01 ? a1 + (f1 - l0) : a2 + (f1 - l01));
            int j2 = f2 < l0 ? a0 + f2 : (f2 < l01 ? a1 + (f2 - l0) : a2 + (f2 - l01));
            int j3 = f3 < l0 ? a0 + f3 : (f3 < l01 ? a1 + (f3 - l0) : a2 + (f3 - l01));
            float4 p0 = gp[j0], p1 = gp[j1], p2 = gp[j2], p3 = gp[j3];
            INS1(p0); INS1(p1); INS1(p2); INS1(p3);
        }
        for (; f < m; f += 8) {
            int j = f < l0 ? a0 + f : (f < l01 ? a1 + (f - l0) : a2 + (f - l01));
            float4 p = gp[j];
            INS1(p);
        }
    }

#define MERGE_P(M) {                                                           \
        float e0 = __shfl_xor(d0, M), e1 = __shfl_xor(d1, M);                  \
        float e2 = __shfl_xor(d2, M), e3 = __shfl_xor(d3, M);                  \
        int j0 = __shfl_xor(i0, M), j1 = __shfl_xor(i1, M);                    \
        int j2 = __shfl_xor(i2, M), j3 = __shfl_xor(i3, M);                    \
        lexins(e0, j0, d0, d1, d2, d3, i0, i1, i2, i3);                        \
        lexins(e1, j1, d0, d1, d2, d3, i0, i1, i2, i3);                        \
        lexins(e2, j2, d0, d1, d2, d3, i0, i1, i2, i3);                        \
        lexins(e3, j3, d0, d1, d2, d3, i0, i1, i2, i3);                        \
    }
#define MERGE_D(M) {                                                           \
        float e0 = __shfl_xor(d0, M), e1 = __shfl_xor(d1, M);                  \
        float e2 = __shfl_xor(d2, M), e3 = __shfl_xor(d3, M);                  \
        int j0 = __shfl_xor(i0, M), j1 = __shfl_xor(i1, M);                    \
        int j2 = __shfl_xor(i2, M), j3 = __shfl_xor(i3, M);                    \
        lexins_d(e0, j0, d0, d1, d2, d3, i0, i1, i2, i3);                      \
        lexins_d(e1, j1, d0, d1, d2, d3, i0, i1, i2, i3);                      \
        lexins_d(e2, j2, d0, d1, d2, d3, i0, i1, i2, i3);                      \
        lexins_d(e3, j3, d0, d1, d2, d3, i0, i1, i2, i3);                      \
    }

    MERGE_P(1);
    MERGE_P(2);
    MERGE_P(4);

    auto done_at = [&](int r) -> bool {
        int bx0 = ix - r, bx1 = ix + r, by0 = iy - r, by1 = iy + r;
        float bound = 1e30f;
        if (bx0 > 0)      bound = fminf(bound, lx - (float)bx0 * CELLH);
        if (bx1 < GC - 1) bound = fminf(bound, (float)(bx1 + 1) * CELLH - lx);
        if (by0 > 0)      bound = fminf(bound, ly - (float)by0 * CELLH);
        if (by1 < GC - 1) bound = fminf(bound, (float)(by1 + 1) * CELLH - ly);
        bool covered = (bx0 <= 0 && bx1 >= GC - 1 && by0 <= 0 && by1 >= GC - 1);
        return covered || (d3 < bound * bound - 1e-5f);
    };

#define SCAN_RANGE_S(JLO, JHI)                                       \
    for (int j = (JLO) + s; j < (JHI); j += 8) {                     \
        float4 p = gp[j];                                            \
        INS1(p);                                                     \
    }

    int r = 1;
    bool need = !done_at(1);
    while (__any(need)) {
        ++r;
        if (need) {
            int ry0 = iy - r, ry1 = iy + r;
            int rx0 = ix - r, rx1 = ix + r;
            int ca = max(rx0, 0), cb = min(rx1, GC - 1);
            if (ry0 >= 0)      { int base = ry0 * GC; SCAN_RANGE_S(cst[base + ca], cst[base + cb + 1]); }
            if (ry1 <= GC - 1) { int base = ry1 * GC; SCAN_RANGE_S(cst[base + ca], cst[base + cb + 1]); }
            int ya = max(ry0 + 1, 0), yb = min(ry1 - 1, GC - 1);
            if (rx0 >= 0)      for (int cy = ya; cy <= yb; ++cy) { int c = cy * GC + rx0; SCAN_RANGE_S(cst[c], cst[c + 1]); }
            if (rx1 <= GC - 1) for (int cy = ya; cy <= yb; ++cy) { int c = cy * GC + rx1; SCAN_RANGE_S(cst[c], cst[c + 1]); }
            MERGE_D(1);
            MERGE_D(2);
            MERGE_D(4);
            need = !done_at(r);
        }
    }
#undef SCAN_RANGE_S
#undef MERGE_P
#undef MERGE_D
#undef INS1

    // ---- tail, split 8-way over channel chunks (t = s) ----
    int bb = bh >> 3, h = bh & 7;
    int qi = (g >> 2) & (NQ - 1);
    float power = fmaxf(sp[0], 0.0f) + 1e-6f;
    int idx[4] = {i0, i1, i2, i3};
    float z[4];
    #pragma unroll
    for (int u = 0; u < 4; ++u) {
        float kx = kvpos[(size_t)(bb * NKV + idx[u]) * 2 + 0];
        float ky = kvpos[(size_t)(bb * NKV + idx[u]) * 2 + 1];
        float dx = kx - lx;
        float dy = ky - ly;
        float dist = sqrtf(dx * dx + dy * dy) + 1e-6f;
        z[u] = -power * dist;
    }
    float m = fmaxf(fmaxf(z[0], z[1]), fmaxf(z[2], z[3]));
    float e0 = expf(z[0] - m), e1 = expf(z[1] - m), e2 = expf(z[2] - m), e3 = expf(z[3] - m);
    float esum = e0 + e1 + e2 + e3;
    float w0 = e0 / esum, w1 = e1 / esum, w2 = e2 / esum, w3 = e3 / esum;

    const float4* vp0 = (const float4*)(vws + ((size_t)bh * NKV + i0) * CH);
    const float4* vp1 = (const float4*)(vws + ((size_t)bh * NKV + i1) * CH);
    const float4* vp2 = (const float4*)(vws + ((size_t)bh * NKV + i2) * CH);
    const float4* vp3 = (const float4*)(vws + ((size_t)bh * NKV + i3) * CH);
    float a = attnw[g];
    float4* hp = (float4*)(head + ((size_t)(bb * NQ + qi)) * D + h * CH);
    {
        float4 x0 = vp0[s], x1 = vp1[s], x2 = vp2[s], x3 = vp3[s];
        float4 rr;
        rr.x = a * (w0 * x0.x + w1 * x1.x + w2 * x2.x + w3 * x3.x);
        rr.y = a * (w0 * x0.y + w1 * x1.y + w2 * x2.y + w3 * x3.y);
        rr.z = a * (w0 * x0.z + w1 * x1.z + w2 * x2.z + w3 * x3.z);
        rr.w = a * (w0 * x0.w + w1 * x1.w + w2 * x2.w + w3 * x3.w);
        rr.x += __shfl_xor(rr.x, 8); rr.x += __shfl_xor(rr.x, 16);  // sum over k
        rr.y += __shfl_xor(rr.y, 8); rr.y += __shfl_xor(rr.y, 16);
        rr.z += __shfl_xor(rr.z, 8); rr.z += __shfl_xor(rr.z, 16);
        rr.w += __shfl_xor(rr.w, 8); rr.w += __shfl_xor(rr.w, 16);
        if (((lane >> 3) & 3) == 0) hp[s] = rr;                     // k==0 lanes write
    }
}

// Fallback (ws too small): brute-force fused scan (round-4 validated path)
__global__ void k_knn_fused(const float* __restrict__ kvpos, const float* __restrict__ loc,
                            const float* __restrict__ attnw, const float* __restrict__ vws,
                            const float* __restrict__ sp, float* __restrict__ head) {
    #pragma clang fp contract(off)
    int g = blockIdx.x * 256 + threadIdx.x;
    int bh = g >> 12;
    int b = bh >> 3;
    __shared__ float sx[NKV];
    __shared__ float sy[NKV];
    __shared__ float sz[NKV];
    for (int n = threadIdx.x; n < NKV; n += 256) {
        float x = kvpos[(size_t)(b * NKV + n) * 2 + 0];
        float y = kvpos[(size_t)(b * NKV + n) * 2 + 1];
        sx[n] = -2.0f * x;
        sy[n] = -2.0f * y;
        sz[n] = x * x + y * y;
    }
    __syncthreads();
    float2 L = ((const float2*)loc)[g];
    float lx = L.x, ly = L.y;
    float sl = lx * lx + ly * ly;
    const float4* x4 = (const float4*)sx;
    const float4* y4 = (const float4*)sy;
    const float4* z4 = (const float4*)sz;
    float d0 = 1e30f, d1 = 1e30f, d2 = 1e30f, d3 = 1e30f;
    int i0 = 0, i1 = 0, i2 = 0, i3 = 0;
    for (int n = 0; n < NKV; n += 4) {
        int v = n >> 2;
        float4 xA = x4[v], yA = y4[v], zA = z4[v];
        float t0 = (sl + zA.x) + fmaf(ly, yA.x, lx * xA.x);
        float t1 = (sl + zA.y) + fmaf(ly, yA.y, lx * xA.y);
        float t2 = (sl + zA.z) + fmaf(ly, yA.z, lx * xA.z);
        float t3 = (sl + zA.w) + fmaf(ly, yA.w, lx * xA.w);
        bins4(t0, n + 0, d0, d1, d2, d3, i0, i1, i2, i3);
        bins4(t1, n + 1, d0, d1, d2, d3, i0, i1, i2, i3);
        bins4(t2, n + 2, d0, d1, d2, d3, i0, i1, i2, i3);
        bins4(t3, n + 3, d0, d1, d2, d3, i0, i1, i2, i3);
    }
    float power = fmaxf(sp[0], 0.0f) + 1e-6f;
    int h = bh & 7;
    int qi = (g >> 2) & (NQ - 1);
    int k = g & 3;
    int idx[4] = {i0, i1, i2, i3};
    float z[4];
    #pragma unroll
    for (int u = 0; u < 4; ++u) {
        float kx = kvpos[(size_t)(b * NKV + idx[u]) * 2 + 0];
        float ky = kvpos[(size_t)(b * NKV + idx[u]) * 2 + 1];
        float dx = kx - lx;
        float dy = ky - ly;
        float dist = sqrtf(dx * dx + dy * dy) + 1e-6f;
        z[u] = -power * dist;
    }
    float m = fmaxf(fmaxf(z[0], z[1]), fmaxf(z[2], z[3]));
    float e0 = expf(z[0] - m), e1 = expf(z[1] - m), e2 = expf(z[2] - m), e3 = expf(z[3] - m);
    float esum = e0 + e1 + e2 + e3;
    float w0 = e0 / esum, w1 = e1 / esum, w2 = e2 / esum, w3 = e3 / esum;
    const float4* vp0 = (const float4*)(vws + ((size_t)bh * NKV + i0) * CH);
    const float4* vp1 = (const float4*)(vws + ((size_t)bh * NKV + i1) * CH);
    const float4* vp2 = (const float4*)(vws + ((size_t)bh * NKV + i2) * CH);
    const float4* vp3 = (const float4*)(vws + ((size_t)bh * NKV + i3) * CH);
    float a = attnw[g];
    float4 acc[8];
    #pragma unroll
    for (int t = 0; t < 8; ++t) {
        float4 x0 = vp0[t], x1 = vp1[t], x2 = vp2[t], x3 = vp3[t];
        float4 r;
        r.x = a * (w0 * x0.x + w1 * x1.x + w2 * x2.x + w3 * x3.x);
        r.y = a * (w0 * x0.y + w1 * x1.y + w2 * x2.y + w3 * x3.y);
        r.z = a * (w0 * x0.z + w1 * x1.z + w2 * x2.z + w3 * x3.z);
        r.w = a * (w0 * x0.w + w1 * x1.w + w2 * x2.w + w3 * x3.w);
        r.x += __shfl_xor(r.x, 1); r.x += __shfl_xor(r.x, 2);
        r.y += __shfl_xor(r.y, 1); r.y += __shfl_xor(r.y, 2);
        r.z += __shfl_xor(r.z, 1); r.z += __shfl_xor(r.z, 2);
        r.w += __shfl_xor(r.w, 1); r.w += __shfl_xor(r.w, 2);
        acc[t] = r;
    }
    float4* hp = (float4*)(head + ((size_t)(b * NQ + qi)) * D + h * CH);
    hp[k * 2]     = acc[k * 2];
    hp[k * 2 + 1] = acc[k * 2 + 1];
}

// ---------------------------------------------------------------------------
// Kernel 4: out = head @ W_out + b_out.  16 rows/block, 4x4 register tile,
// float4 weight loads + float4 stores.
// ---------------------------------------------------------------------------
__global__ void k_out(const float* __restrict__ head, const float* __restrict__ Wout,
                      const float* __restrict__ bout, float* __restrict__ out) {
    int r0 = blockIdx.x * 16;
    __shared__ float hs[16][D];      // 16 KB
    for (int t = threadIdx.x; t < 16 * D; t += 256) hs[t >> 8][t & 255] = head[(size_t)r0 * D + t];
    __syncthreads();
    int cg = threadIdx.x & 63;
    int rg = threadIdx.x >> 6;
    float4 a0 = {0,0,0,0}, a1 = {0,0,0,0}, a2 = {0,0,0,0}, a3 = {0,0,0,0};
    for (int d = 0; d < D; ++d) {
        float4 w = *(const float4*)&Wout[d * D + cg * 4];
        float k0 = hs[rg * 4 + 0][d], k1 = hs[rg * 4 + 1][d];
        float k2 = hs[rg * 4 + 2][d], k3 = hs[rg * 4 + 3][d];
        a0.x = fmaf(k0, w.x, a0.x); a0.y = fmaf(k0, w.y, a0.y); a0.z = fmaf(k0, w.z, a0.z); a0.w = fmaf(k0, w.w, a0.w);
        a1.x = fmaf(k1, w.x, a1.x); a1.y = fmaf(k1, w.y, a1.y); a1.z = fmaf(k1, w.z, a1.z); a1.w = fmaf(k1, w.w, a1.w);
        a2.x = fmaf(k2, w.x, a2.x); a2.y = fmaf(k2, w.y, a2.y); a2.z = fmaf(k2, w.z, a2.z); a2.w = fmaf(k2, w.w, a2.w);
        a3.x = fmaf(k3, w.x, a3.x); a3.y = fmaf(k3, w.y, a3.y); a3.z = fmaf(k3, w.z, a3.z); a3.w = fmaf(k3, w.w, a3.w);
    }
    float4 bias = *(const float4*)&bout[cg * 4];
    float4 va[4] = {a0, a1, a2, a3};
    #pragma unroll
    for (int rr = 0; rr < 4; ++rr) {
        int row = r0 + rg * 4 + rr;
        float4 v;
        v.x = va[rr].x + bias.x; v.y = va[rr].y + bias.y;
        v.z = va[rr].z + bias.z; v.w = va[rr].w + bias.w;
        *(float4*)&out[(size_t)row * D + cg * 4] = v;
    }
}

// ---------------------------------------------------------------------------
extern "C" void kernel_launch(void* const* d_in, const int* in_sizes, int n_in,
                              void* d_out, int out_size, void* d_ws, size_t ws_size,
                              hipStream_t stream) {
    (void)in_sizes; (void)n_in; (void)out_size;
    const float* q     = (const float*)d_in[0];
    const float* qpos  = (const float*)d_in[1];
    const float* kv    = (const float*)d_in[2];
    const float* kvp   = (const float*)d_in[3];
    const float* Woff  = (const float*)d_in[4];
    const float* boff  = (const float*)d_in[5];
    const float* Wattn = (const float*)d_in[6];
    const float* battn = (const float*)d_in[7];
    const float* Wv    = (const float*)d_in[8];
    const float* bv    = (const float*)d_in[9];
    const float* Wout  = (const float*)d_in[10];
    const float* bout  = (const float*)d_in[11];
    const float* sp    = (const float*)d_in[12];
    float* out = (float*)d_out;

    char* ws = (char*)d_ws;
    float* loc      = (float*)(ws + OFF_LOC);
    float* attnw    = (float*)(ws + OFF_ATTN);
    float* vws      = (float*)(ws + OFF_VWS);
    float* head     = (float*)(ws + OFF_HEAD);
    float4* pts4    = (float4*)(ws + OFF_PTS);
    int* cellStart  = (int*)(ws + OFF_CST);

    bool grid_ok = ws_size >= (size_t)WS_NEED;
    int nblk = (BATCH * NQ) / 8 + (grid_ok ? BATCH : 0);
    hipLaunchKernelGGL(k_offattn_bin, dim3(nblk), dim3(128), 0, stream,
                       q, qpos, Woff, boff, Wattn, battn, kvp, loc, attnw, pts4, cellStart);
    hipLaunchKernelGGL(k_values, dim3(BATCH * NKV / 16), dim3(256), 0, stream,
                       kv, Wv, bv, vws);
    if (grid_ok) {
        hipLaunchKernelGGL(k_knn_grid2, dim3(BATCH * H * NQ * K / 32), dim3(256), 0, stream,
                           kvp, loc, attnw, vws, sp, pts4, cellStart, head);
    } else {
        hipLaunchKernelGGL(k_knn_fused, dim3(BATCH * H * NQ * K / 256), dim3(256), 0, stream,
                           kvp, loc, attnw, vws, sp, head);
    }
    hipLaunchKernelGGL(k_out, dim3(BATCH * NQ / 16), dim3(256), 0, stream,
                       head, Wout, bout, out);
}

// Round 15
// 114.686 us; speedup vs baseline: 14.5956x; 1.2068x over previous
//
#include <hip/hip_runtime.h>
#include <hip/hip_bf16.h>
#include <math.h>

#define H 8
#define K 4
#define NN 4
#define D 256
#define NQ 1024
#define NKV 2048
#define BATCH 2
#define CH 32           // D / H
#define GC 16           // grid cells per axis
#define CELLH 0.0625f   // 1/16

// workspace layout (bytes) — vws now bf16 (2 MB used of the 4 MB slot)
#define OFF_LOC   0u          // 65536 * float2 = 512 KB
#define OFF_ATTN  524288u     // 65536 * f32    = 256 KB
#define OFF_VWS   786432u     // 16*2048*32 bf16 = 2 MB (slot sized 4 MB)
#define OFF_HEAD  4980736u    // 2*1024*256 f32 = 2 MB
#define OFF_PTS   7077888u    // 2*2048 float4  = 64 KB (cell-sorted)
#define OFF_CST   7143424u    // 2*257 i32 cell starts (+pad)
#define WS_NEED   7147520u

typedef unsigned short ushortb;

__device__ __forceinline__ float bf2f(ushortb u) {
    return __uint_as_float((unsigned)u << 16);
}
__device__ __forceinline__ ushortb f2bf(float f) {
    __hip_bfloat16 h = __float2bfloat16(f);       // RNE
    return *(ushortb*)&h;
}

// ---------------------------------------------------------------------------
// Branchless lexicographic (d, idx) stable top-4 insert — f32/i32 only.
// Order-independent; reproduces lax.top_k (d asc, ties idx asc).
// ---------------------------------------------------------------------------
__device__ __forceinline__ void lexins(float t, int n,
                                       float& d0, float& d1, float& d2, float& d3,
                                       int& i0, int& i1, int& i2, int& i3) {
    bool c0 = (t < d0) || (t == d0 && n < i0);
    bool c1 = (t < d1) || (t == d1 && n < i1);
    bool c2 = (t < d2) || (t == d2 && n < i2);
    bool c3 = (t < d3) || (t == d3 && n < i3);
    d3 = c3 ? (c2 ? d2 : t) : d3;   i3 = c3 ? (c2 ? i2 : n) : i3;
    d2 = c2 ? (c1 ? d1 : t) : d2;   i2 = c2 ? (c1 ? i1 : n) : i2;
    d1 = c1 ? (c0 ? d0 : t) : d1;   i1 = c1 ? (c0 ? i0 : n) : i1;
    d0 = c0 ? t : d0;               i0 = c0 ? n : i0;
}

// DEDUP variant: for ring re-merges where lists share phase-1 survivors.
__device__ __forceinline__ void lexins_d(float t, int n,
                                         float& d0, float& d1, float& d2, float& d3,
                                         int& i0, int& i1, int& i2, int& i3) {
    bool nd = !((n == i0) | (n == i1) | (n == i2) | (n == i3));
    bool c0 = nd && ((t < d0) || (t == d0 && n < i0));
    bool c1 = nd && ((t < d1) || (t == d1 && n < i1));
    bool c2 = nd && ((t < d2) || (t == d2 && n < i2));
    bool c3 = nd && ((t < d3) || (t == d3 && n < i3));
    d3 = c3 ? (c2 ? d2 : t) : d3;   i3 = c3 ? (c2 ? i2 : n) : i3;
    d2 = c2 ? (c1 ? d1 : t) : d2;   i2 = c2 ? (c1 ? i1 : n) : i2;
    d1 = c1 ? (c0 ? d0 : t) : d1;   i1 = c1 ? (c0 ? i0 : n) : i1;
    d0 = c0 ? t : d0;               i0 = c0 ? n : i0;
}

// strict-< variant for the ascending-order brute-force fallback
__device__ __forceinline__ void bins4(float t, int n,
                                      float& d0, float& d1, float& d2, float& d3,
                                      int& i0, int& i1, int& i2, int& i3) {
    bool c0 = t < d0, c1 = t < d1, c2 = t < d2, c3 = t < d3;
    d3 = c3 ? (c2 ? d2 : t) : d3;   i3 = c3 ? (c2 ? i2 : n) : i3;
    d2 = c2 ? (c1 ? d1 : t) : d2;   i2 = c2 ? (c1 ? i1 : n) : i2;
    d1 = c1 ? (c0 ? d0 : t) : d1;   i1 = c1 ? (c0 ? i0 : n) : i1;
    d0 = c0 ? t : d0;               i0 = c0 ? n : i0;
}

// ---------------------------------------------------------------------------
// Kernel 1: off = q@W_off + b_off (sequential fmaf chain = Eigen/oneDNN sgemm
// semantics, bias after) -> loc; attn = softmax_K(q@W_attn + b_attn)
// (R9-validated version: 1 row/block, 2048 blocks — good occupancy)
// ---------------------------------------------------------------------------
__global__ void k_offattn(const float* __restrict__ q, const float* __restrict__ qpos,
                          const float* __restrict__ Woff, const float* __restrict__ boff,
                          const float* __restrict__ Wattn, const float* __restrict__ battn,
                          float* __restrict__ loc, float* __restrict__ attnw) {
    #pragma clang fp contract(off)
    int row = blockIdx.x;            // b*NQ + q
    int b = row >> 10, qi = row & (NQ - 1);
    __shared__ float qs[D];
    for (int d = threadIdx.x; d < D; d += blockDim.x) qs[d] = q[(size_t)row * D + d];
    __syncthreads();
    int j = threadIdx.x;
    if (j < 64) {
        float acc = 0.0f;
        for (int d = 0; d < D; ++d) acc = fmaf(qs[d], Woff[d * 64 + j], acc);
        float off = acc + boff[j];               // bias after, like np
        int xy = j & 1;
        int hk = j >> 1;                         // h*4 + k
        int h = hk >> 2, k = hk & 3;
        float L = qpos[(size_t)row * 2 + xy] + off;
        int g = ((b * H + h) * NQ + qi) * K + k;
        loc[(size_t)g * 2 + xy] = L;
    } else if (j < 96) {
        int j2 = j - 64;                         // h*4 + k
        float acc = 0.0f;
        for (int d = 0; d < D; ++d) acc = fmaf(qs[d], Wattn[d * 32 + j2], acc);
        acc += battn[j2];
        float m = acc;
        m = fmaxf(m, __shfl_xor(m, 1));
        m = fmaxf(m, __shfl_xor(m, 2));
        float e = expf(acc - m);
        float s = e;
        s += __shfl_xor(s, 1);
        s += __shfl_xor(s, 2);
        float w = e / s;
        int h = j2 >> 2, k = j2 & 3;
        attnw[((b * H + h) * NQ + qi) * K + k] = w;
    }
}

// ---------------------------------------------------------------------------
// Kernel 2: values = kv @ W_v + b_v, stored transposed as [b*H][n_kv][32]
// **bf16** (RNE).  R9 structure (4 rows/block, 1024 blocks).
// ---------------------------------------------------------------------------
__global__ void k_values(const float* __restrict__ kv, const float* __restrict__ Wv,
                         const float* __restrict__ bv, ushortb* __restrict__ vwsb) {
    int r0 = blockIdx.x * 4;         // row = b*NKV + n
    __shared__ float ks[4][D];
    for (int t = threadIdx.x; t < 4 * D; t += 256) ks[t >> 8][t & 255] = kv[(size_t)r0 * D + t];
    __syncthreads();
    int c = threadIdx.x;             // h*32 + cc
    float a0 = 0.f, a1 = 0.f, a2 = 0.f, a3 = 0.f;
    for (int d = 0; d < D; ++d) {
        float w = Wv[d * D + c];
        a0 = fmaf(ks[0][d], w, a0); a1 = fmaf(ks[1][d], w, a1);
        a2 = fmaf(ks[2][d], w, a2); a3 = fmaf(ks[3][d], w, a3);
    }
    float bias = bv[c];
    a0 += bias; a1 += bias; a2 += bias; a3 += bias;
    int h = c >> 5, cc = c & 31;
    float va[4] = {a0, a1, a2, a3};
    for (int r = 0; r < 4; ++r) {
        int row = r0 + r;
        int b = row >> 11, n = row & (NKV - 1);
        vwsb[(((size_t)(b * H + h) * NKV) + n) * CH + cc] = f2bf(va[r]);
    }
}

// ---------------------------------------------------------------------------
// Kernel B: bin kv points into 16x16 cells (per batch), cell-sorted float4
// (-2x, -2y, x^2+y^2, (float)origIdx) + cellStart[257].
// ---------------------------------------------------------------------------
__global__ void k_bin(const float* __restrict__ kvpos, float4* __restrict__ pts4,
                      int* __restrict__ cellStart) {
    #pragma clang fp contract(off)
    int b = blockIdx.x;
    int tid = threadIdx.x;
    __shared__ int cnt[GC * GC];
    __shared__ int ofs[GC * GC + 1];
    __shared__ int cur[GC * GC];
    if (tid < GC * GC) cnt[tid] = 0;
    __syncthreads();
    for (int n = tid; n < NKV; n += 256) {
        float x = kvpos[(size_t)(b * NKV + n) * 2 + 0];
        float y = kvpos[(size_t)(b * NKV + n) * 2 + 1];
        int ix = min(GC - 1, max(0, (int)floorf(x * (float)GC)));
        int iy = min(GC - 1, max(0, (int)floorf(y * (float)GC)));
        atomicAdd(&cnt[iy * GC + ix], 1);
    }
    __syncthreads();
    if (tid == 0) {
        int s = 0;
        for (int c = 0; c < GC * GC; ++c) { ofs[c] = s; s += cnt[c]; }
        ofs[GC * GC] = s;
    }
    __syncthreads();
    for (int t = tid; t < GC * GC + 1; t += 256) cellStart[b * 257 + t] = ofs[t];
    if (tid < GC * GC) cur[tid] = ofs[tid];
    __syncthreads();
    for (int n = tid; n < NKV; n += 256) {
        float x = kvpos[(size_t)(b * NKV + n) * 2 + 0];
        float y = kvpos[(size_t)(b * NKV + n) * 2 + 1];
        int ix = min(GC - 1, max(0, (int)floorf(x * (float)GC)));
        int iy = min(GC - 1, max(0, (int)floorf(y * (float)GC)));
        int pos = atomicAdd(&cur[iy * GC + ix], 1);
        pts4[(size_t)b * NKV + pos] = make_float4(-2.0f * x, -2.0f * y, x * x + y * y, (float)n);
    }
}

// ---------------------------------------------------------------------------
// Kernel 3 (R9-validated structure): grid 4-NN, 8 lanes/point, 3x3 box +
// ring, flattened rows + 4-wide batched loads, inline tail (bf16 gather).
// ---------------------------------------------------------------------------
__global__ void k_knn_grid2(const float* __restrict__ kvpos, const float* __restrict__ loc,
                            const float* __restrict__ attnw, const ushortb* __restrict__ vwsb,
                            const float* __restrict__ sp,
                            const float4* __restrict__ pts4, const int* __restrict__ cellStart,
                            float* __restrict__ head) {
    #pragma clang fp contract(off)
    int lane = threadIdx.x;
    int s = lane & 7;
    int g = blockIdx.x * 32 + (lane >> 3);    // point id
    int b = g >> 15;
    int bh = g >> 12;

    __shared__ int cst[GC * GC + 1];
    for (int i = threadIdx.x; i < GC * GC + 1; i += 256) cst[i] = cellStart[b * 257 + i];
    __syncthreads();

    const float4* gp = pts4 + (size_t)b * NKV;
    float2 L = ((const float2*)loc)[g];
    float lx = L.x, ly = L.y;
    float sl = lx * lx + ly * ly;

    int ix = min(GC - 1, max(0, (int)floorf(lx * (float)GC)));
    int iy = min(GC - 1, max(0, (int)floorf(ly * (float)GC)));

    float d0 = 1e30f, d1 = 1e30f, d2 = 1e30f, d3 = 1e30f;
    int i0 = 0x7FFFFFFF, i1 = 0x7FFFFFFF, i2 = 0x7FFFFFFF, i3 = 0x7FFFFFFF;

#define INS1(P) { float tt = (sl + (P).z) + fmaf(ly, (P).y, lx * (P).x);      \
                  lexins(tt, (int)(P).w, d0, d1, d2, d3, i0, i1, i2, i3); }

    // ---- phase 1: clamped 3x3 box, flattened rows, 4-wide batched loads ----
    {
        int bx0 = max(ix - 1, 0), bx1 = min(ix + 1, GC - 1);
        int by0 = max(iy - 1, 0), by1 = min(iy + 1, GC - 1);
        int a0 = cst[by0 * GC + bx0];
        int l0 = cst[by0 * GC + bx1 + 1] - a0;
        int a1 = 0, l1 = 0, a2 = 0, l2 = 0;
        if (by0 + 1 <= by1) { a1 = cst[(by0 + 1) * GC + bx0]; l1 = cst[(by0 + 1) * GC + bx1 + 1] - a1; }
        if (by0 + 2 <= by1) { a2 = cst[(by0 + 2) * GC + bx0]; l2 = cst[(by0 + 2) * GC + bx1 + 1] - a2; }
        int l01 = l0 + l1;
        int m = l01 + l2;
        int f = s;
        for (; f + 24 < m; f += 32) {
            int f0 = f, f1 = f + 8, f2 = f + 16, f3 = f + 24;
            int j0 = f0 < l0 ? a0 + f0 : (f0 < l01 ? a1 + (f0 - l0) : a2 + (f0 - l01));
            int j1 = f1 < l0 ? a0 + f1 : (f1 < l01 ? a1 + (f1 - l0) : a2 + (f1 - l01));
            int j2 = f2 < l0 ? a0 + f2 : (f2 < l01 ? a1 + (f2 - l0) : a2 + (f2 - l01));
            int j3 = f3 < l0 ? a0 + f3 : (f3 < l01 ? a1 + (f3 - l0) : a2 + (f3 - l01));
            float4 p0 = gp[j0], p1 = gp[j1], p2 = gp[j2], p3 = gp[j3];
            INS1(p0); INS1(p1); INS1(p2); INS1(p3);
        }
        for (; f < m; f += 8) {
            int j = f < l0 ? a0 + f : (f < l01 ? a1 + (f - l0) : a2 + (f - l01));
            float4 p = gp[j];
            INS1(p);
        }
    }

#define MERGE_P(M) {                                                           \
        float e0 = __shfl_xor(d0, M), e1 = __shfl_xor(d1, M);                  \
        float e2 = __shfl_xor(d2, M), e3 = __shfl_xor(d3, M);                  \
        int j0 = __shfl_xor(i0, M), j1 = __shfl_xor(i1, M);                    \
        int j2 = __shfl_xor(i2, M), j3 = __shfl_xor(i3, M);                    \
        lexins(e0, j0, d0, d1, d2, d3, i0, i1, i2, i3);                        \
        lexins(e1, j1, d0, d1, d2, d3, i0, i1, i2, i3);                        \
        lexins(e2, j2, d0, d1, d2, d3, i0, i1, i2, i3);                        \
        lexins(e3, j3, d0, d1, d2, d3, i0, i1, i2, i3);                        \
    }
#define MERGE_D(M) {                                                           \
        float e0 = __shfl_xor(d0, M), e1 = __shfl_xor(d1, M);                  \
        float e2 = __shfl_xor(d2, M), e3 = __shfl_xor(d3, M);                  \
        int j0 = __shfl_xor(i0, M), j1 = __shfl_xor(i1, M);                    \
        int j2 = __shfl_xor(i2, M), j3 = __shfl_xor(i3, M);                    \
        lexins_d(e0, j0, d0, d1, d2, d3, i0, i1, i2, i3);                      \
        lexins_d(e1, j1, d0, d1, d2, d3, i0, i1, i2, i3);                      \
        lexins_d(e2, j2, d0, d1, d2, d3, i0, i1, i2, i3);                      \
        lexins_d(e3, j3, d0, d1, d2, d3, i0, i1, i2, i3);                      \
    }

    MERGE_P(1);
    MERGE_P(2);
    MERGE_P(4);

    auto done_at = [&](int r) -> bool {
        int bx0 = ix - r, bx1 = ix + r, by0 = iy - r, by1 = iy + r;
        float bound = 1e30f;
        if (bx0 > 0)      bound = fminf(bound, lx - (float)bx0 * CELLH);
        if (bx1 < GC - 1) bound = fminf(bound, (float)(bx1 + 1) * CELLH - lx);
        if (by0 > 0)      bound = fminf(bound, ly - (float)by0 * CELLH);
        if (by1 < GC - 1) bound = fminf(bound, (float)(by1 + 1) * CELLH - ly);
        bool covered = (bx0 <= 0 && bx1 >= GC - 1 && by0 <= 0 && by1 >= GC - 1);
        return covered || (d3 < bound * bound - 1e-5f);
    };

#define SCAN_RANGE_S(JLO, JHI)                                       \
    for (int j = (JLO) + s; j < (JHI); j += 8) {                     \
        float4 p = gp[j];                                            \
        INS1(p);                                                     \
    }

    int r = 1;
    bool need = !done_at(1);
    while (__any(need)) {
        ++r;
        if (need) {
            int ry0 = iy - r, ry1 = iy + r;
            int rx0 = ix - r, rx1 = ix + r;
            int ca = max(rx0, 0), cb = min(rx1, GC - 1);
            if (ry0 >= 0)      { int base = ry0 * GC; SCAN_RANGE_S(cst[base + ca], cst[base + cb + 1]); }
            if (ry1 <= GC - 1) { int base = ry1 * GC; SCAN_RANGE_S(cst[base + ca], cst[base + cb + 1]); }
            int ya = max(ry0 + 1, 0), yb = min(ry1 - 1, GC - 1);
            if (rx0 >= 0)      for (int cy = ya; cy <= yb; ++cy) { int c = cy * GC + rx0; SCAN_RANGE_S(cst[c], cst[c + 1]); }
            if (rx1 <= GC - 1) for (int cy = ya; cy <= yb; ++cy) { int c = cy * GC + rx1; SCAN_RANGE_S(cst[c], cst[c + 1]); }
            MERGE_D(1);
            MERGE_D(2);
            MERGE_D(4);
            need = !done_at(r);
        }
    }
#undef SCAN_RANGE_S
#undef MERGE_P
#undef MERGE_D
#undef INS1

    // ---- tail, split 8-way over channel chunks (t = s), bf16 gather ----
    int bb = bh >> 3, h = bh & 7;
    int qi = (g >> 2) & (NQ - 1);
    float power = fmaxf(sp[0], 0.0f) + 1e-6f;
    int idx[4] = {i0, i1, i2, i3};
    float z[4];
    #pragma unroll
    for (int u = 0; u < 4; ++u) {
        float kx = kvpos[(size_t)(bb * NKV + idx[u]) * 2 + 0];
        float ky = kvpos[(size_t)(bb * NKV + idx[u]) * 2 + 1];
        float dx = kx - lx;
        float dy = ky - ly;
        float dist = sqrtf(dx * dx + dy * dy) + 1e-6f;
        z[u] = -power * dist;
    }
    float m = fmaxf(fmaxf(z[0], z[1]), fmaxf(z[2], z[3]));
    float e0 = expf(z[0] - m), e1 = expf(z[1] - m), e2 = expf(z[2] - m), e3 = expf(z[3] - m);
    float esum = e0 + e1 + e2 + e3;
    float w0 = e0 / esum, w1 = e1 / esum, w2 = e2 / esum, w3 = e3 / esum;

    const ushort4* vp0 = (const ushort4*)(vwsb + ((size_t)bh * NKV + i0) * CH);
    const ushort4* vp1 = (const ushort4*)(vwsb + ((size_t)bh * NKV + i1) * CH);
    const ushort4* vp2 = (const ushort4*)(vwsb + ((size_t)bh * NKV + i2) * CH);
    const ushort4* vp3 = (const ushort4*)(vwsb + ((size_t)bh * NKV + i3) * CH);
    float a = attnw[g];
    float4* hp = (float4*)(head + ((size_t)(bb * NQ + qi)) * D + h * CH);
    {
        ushort4 u0 = vp0[s], u1 = vp1[s], u2 = vp2[s], u3 = vp3[s];
        float4 rr;
        rr.x = a * (w0 * bf2f(u0.x) + w1 * bf2f(u1.x) + w2 * bf2f(u2.x) + w3 * bf2f(u3.x));
        rr.y = a * (w0 * bf2f(u0.y) + w1 * bf2f(u1.y) + w2 * bf2f(u2.y) + w3 * bf2f(u3.y));
        rr.z = a * (w0 * bf2f(u0.z) + w1 * bf2f(u1.z) + w2 * bf2f(u2.z) + w3 * bf2f(u3.z));
        rr.w = a * (w0 * bf2f(u0.w) + w1 * bf2f(u1.w) + w2 * bf2f(u2.w) + w3 * bf2f(u3.w));
        rr.x += __shfl_xor(rr.x, 8); rr.x += __shfl_xor(rr.x, 16);  // sum over k
        rr.y += __shfl_xor(rr.y, 8); rr.y += __shfl_xor(rr.y, 16);
        rr.z += __shfl_xor(rr.z, 8); rr.z += __shfl_xor(rr.z, 16);
        rr.w += __shfl_xor(rr.w, 8); rr.w += __shfl_xor(rr.w, 16);
        if (((lane >> 3) & 3) == 0) hp[s] = rr;                     // k==0 lanes write
    }
}

// Fallback (ws too small): brute-force fused scan (round-4 validated path,
// bf16 value gather)
__global__ void k_knn_fused(const float* __restrict__ kvpos, const float* __restrict__ loc,
                            const float* __restrict__ attnw, const ushortb* __restrict__ vwsb,
                            const float* __restrict__ sp, float* __restrict__ head) {
    #pragma clang fp contract(off)
    int g = blockIdx.x * 256 + threadIdx.x;
    int bh = g >> 12;
    int b = bh >> 3;
    __shared__ float sx[NKV];
    __shared__ float sy[NKV];
    __shared__ float sz[NKV];
    for (int n = threadIdx.x; n < NKV; n += 256) {
        float x = kvpos[(size_t)(b * NKV + n) * 2 + 0];
        float y = kvpos[(size_t)(b * NKV + n) * 2 + 1];
        sx[n] = -2.0f * x;
        sy[n] = -2.0f * y;
        sz[n] = x * x + y * y;
    }
    __syncthreads();
    float2 L = ((const float2*)loc)[g];
    float lx = L.x, ly = L.y;
    float sl = lx * lx + ly * ly;
    const float4* x4 = (const float4*)sx;
    const float4* y4 = (const float4*)sy;
    const float4* z4 = (const float4*)sz;
    float d0 = 1e30f, d1 = 1e30f, d2 = 1e30f, d3 = 1e30f;
    int i0 = 0, i1 = 0, i2 = 0, i3 = 0;
    for (int n = 0; n < NKV; n += 4) {
        int v = n >> 2;
        float4 xA = x4[v], yA = y4[v], zA = z4[v];
        float t0 = (sl + zA.x) + fmaf(ly, yA.x, lx * xA.x);
        float t1 = (sl + zA.y) + fmaf(ly, yA.y, lx * xA.y);
        float t2 = (sl + zA.z) + fmaf(ly, yA.z, lx * xA.z);
        float t3 = (sl + zA.w) + fmaf(ly, yA.w, lx * xA.w);
        bins4(t0, n + 0, d0, d1, d2, d3, i0, i1, i2, i3);
        bins4(t1, n + 1, d0, d1, d2, d3, i0, i1, i2, i3);
        bins4(t2, n + 2, d0, d1, d2, d3, i0, i1, i2, i3);
        bins4(t3, n + 3, d0, d1, d2, d3, i0, i1, i2, i3);
    }
    float power = fmaxf(sp[0], 0.0f) + 1e-6f;
    int h = bh & 7;
    int qi = (g >> 2) & (NQ - 1);
    int k = g & 3;
    int idx[4] = {i0, i1, i2, i3};
    float z[4];
    #pragma unroll
    for (int u = 0; u < 4; ++u) {
        float kx = kvpos[(size_t)(b * NKV + idx[u]) * 2 + 0];
        float ky = kvpos[(size_t)(b * NKV + idx[u]) * 2 + 1];
        float dx = kx - lx;
        float dy = ky - ly;
        float dist = sqrtf(dx * dx + dy * dy) + 1e-6f;
        z[u] = -power * dist;
    }
    float m = fmaxf(fmaxf(z[0], z[1]), fmaxf(z[2], z[3]));
    float e0 = expf(z[0] - m), e1 = expf(z[1] - m), e2 = expf(z[2] - m), e3 = expf(z[3] - m);
    float esum = e0 + e1 + e2 + e3;
    float w0 = e0 / esum, w1 = e1 / esum, w2 = e2 / esum, w3 = e3 / esum;
    const ushort4* vp0 = (const ushort4*)(vwsb + ((size_t)bh * NKV + i0) * CH);
    const ushort4* vp1 = (const ushort4*)(vwsb + ((size_t)bh * NKV + i1) * CH);
    const ushort4* vp2 = (const ushort4*)(vwsb + ((size_t)bh * NKV + i2) * CH);
    const ushort4* vp3 = (const ushort4*)(vwsb + ((size_t)bh * NKV + i3) * CH);
    float a = attnw[g];
    float4 acc[8];
    #pragma unroll
    for (int t = 0; t < 8; ++t) {
        ushort4 u0 = vp0[t], u1 = vp1[t], u2 = vp2[t], u3 = vp3[t];
        float4 r;
        r.x = a * (w0 * bf2f(u0.x) + w1 * bf2f(u1.x) + w2 * bf2f(u2.x) + w3 * bf2f(u3.x));
        r.y = a * (w0 * bf2f(u0.y) + w1 * bf2f(u1.y) + w2 * bf2f(u2.y) + w3 * bf2f(u3.y));
        r.z = a * (w0 * bf2f(u0.z) + w1 * bf2f(u1.z) + w2 * bf2f(u2.z) + w3 * bf2f(u3.z));
        r.w = a * (w0 * bf2f(u0.w) + w1 * bf2f(u1.w) + w2 * bf2f(u2.w) + w3 * bf2f(u3.w));
        r.x += __shfl_xor(r.x, 1); r.x += __shfl_xor(r.x, 2);
        r.y += __shfl_xor(r.y, 1); r.y += __shfl_xor(r.y, 2);
        r.z += __shfl_xor(r.z, 1); r.z += __shfl_xor(r.z, 2);
        r.w += __shfl_xor(r.w, 1); r.w += __shfl_xor(r.w, 2);
        acc[t] = r;
    }
    float4* hp = (float4*)(head + ((size_t)(b * NQ + qi)) * D + h * CH);
    hp[k * 2]     = acc[k * 2];
    hp[k * 2 + 1] = acc[k * 2 + 1];
}

// ---------------------------------------------------------------------------
// Kernel 4: out = head @ W_out + b_out  (f32 store; R9 version, 4 rows/block)
// ---------------------------------------------------------------------------
__global__ void k_out(const float* __restrict__ head, const float* __restrict__ Wout,
                      const float* __restrict__ bout, float* __restrict__ out) {
    int r0 = blockIdx.x * 4;
    __shared__ float hs[4][D];
    for (int t = threadIdx.x; t < 4 * D; t += 256) hs[t >> 8][t & 255] = head[(size_t)r0 * D + t];
    __syncthreads();
    int c = threadIdx.x;
    float a0 = 0.f, a1 = 0.f, a2 = 0.f, a3 = 0.f;
    for (int d = 0; d < D; ++d) {
        float w = Wout[d * D + c];
        a0 = fmaf(hs[0][d], w, a0); a1 = fmaf(hs[1][d], w, a1);
        a2 = fmaf(hs[2][d], w, a2); a3 = fmaf(hs[3][d], w, a3);
    }
    float bias = bout[c];
    out[(size_t)(r0 + 0) * D + c] = a0 + bias;
    out[(size_t)(r0 + 1) * D + c] = a1 + bias;
    out[(size_t)(r0 + 2) * D + c] = a2 + bias;
    out[(size_t)(r0 + 3) * D + c] = a3 + bias;
}

// ---------------------------------------------------------------------------
extern "C" void kernel_launch(void* const* d_in, const int* in_sizes, int n_in,
                              void* d_out, int out_size, void* d_ws, size_t ws_size,
                              hipStream_t stream) {
    (void)in_sizes; (void)n_in; (void)out_size;
    const float* q     = (const float*)d_in[0];
    const float* qpos  = (const float*)d_in[1];
    const float* kv    = (const float*)d_in[2];
    const float* kvp   = (const float*)d_in[3];
    const float* Woff  = (const float*)d_in[4];
    const float* boff  = (const float*)d_in[5];
    const float* Wattn = (const float*)d_in[6];
    const float* battn = (const float*)d_in[7];
    const float* Wv    = (const float*)d_in[8];
    const float* bv    = (const float*)d_in[9];
    const float* Wout  = (const float*)d_in[10];
    const float* bout  = (const float*)d_in[11];
    const float* sp    = (const float*)d_in[12];
    float* out = (float*)d_out;

    char* ws = (char*)d_ws;
    float* loc      = (float*)(ws + OFF_LOC);
    float* attnw    = (float*)(ws + OFF_ATTN);
    ushortb* vwsb   = (ushortb*)(ws + OFF_VWS);
    float* head     = (float*)(ws + OFF_HEAD);
    float4* pts4    = (float4*)(ws + OFF_PTS);
    int* cellStart  = (int*)(ws + OFF_CST);

    hipLaunchKernelGGL(k_offattn, dim3(BATCH * NQ), dim3(128), 0, stream,
                       q, qpos, Woff, boff, Wattn, battn, loc, attnw);
    hipLaunchKernelGGL(k_values, dim3(BATCH * NKV / 4), dim3(256), 0, stream,
                       kv, Wv, bv, vwsb);
    if (ws_size >= (size_t)WS_NEED) {
        hipLaunchKernelGGL(k_bin, dim3(BATCH), dim3(256), 0, stream,
                           kvp, pts4, cellStart);
        hipLaunchKernelGGL(k_knn_grid2, dim3(BATCH * H * NQ * K / 32), dim3(256), 0, stream,
                           kvp, loc, attnw, vwsb, sp, pts4, cellStart, head);
    } else {
        hipLaunchKernelGGL(k_knn_fused, dim3(BATCH * H * NQ * K / 256), dim3(256), 0, stream,
                           kvp, loc, attnw, vwsb, sp, head);
    }
    hipLaunchKernelGGL(k_out, dim3(BATCH * NQ / 4), dim3(256), 0, stream,
                       head, Wout, bout, out);
}

// Round 16
// 102.804 us; speedup vs baseline: 16.2827x; 1.1156x over previous
//
#include <hip/hip_runtime.h>
#include <hip/hip_bf16.h>
#include <math.h>

#define H 8
#define K 4
#define NN 4
#define D 256
#define NQ 1024
#define NKV 2048
#define BATCH 2
#define CH 32           // D / H
#define GC 16           // grid cells per axis
#define CELLH 0.0625f   // 1/16

// workspace layout (bytes) — vws bf16 (2 MB used of the 4 MB slot)
#define OFF_LOC   0u          // 65536 * float2 = 512 KB
#define OFF_ATTN  524288u     // 65536 * f32    = 256 KB
#define OFF_VWS   786432u     // 16*2048*32 bf16 = 2 MB (slot sized 4 MB)
#define OFF_HEAD  4980736u    // 2*1024*256 f32 = 2 MB
#define OFF_PTS   7077888u    // 2*2048 float4  = 64 KB (cell-sorted)
#define OFF_CST   7143424u    // 2*257 i32 cell starts (+pad)
#define WS_NEED   7147520u

typedef unsigned short ushortb;

__device__ __forceinline__ float bf2f(ushortb u) {
    return __uint_as_float((unsigned)u << 16);
}
__device__ __forceinline__ ushortb f2bf(float f) {
    __hip_bfloat16 h = __float2bfloat16(f);       // RNE
    return *(ushortb*)&h;
}

// ---------------------------------------------------------------------------
// Branchless lexicographic (d, idx) stable top-4 insert — f32/i32 only.
// Order-independent; reproduces lax.top_k (d asc, ties idx asc).
// ---------------------------------------------------------------------------
__device__ __forceinline__ void lexins(float t, int n,
                                       float& d0, float& d1, float& d2, float& d3,
                                       int& i0, int& i1, int& i2, int& i3) {
    bool c0 = (t < d0) || (t == d0 && n < i0);
    bool c1 = (t < d1) || (t == d1 && n < i1);
    bool c2 = (t < d2) || (t == d2 && n < i2);
    bool c3 = (t < d3) || (t == d3 && n < i3);
    d3 = c3 ? (c2 ? d2 : t) : d3;   i3 = c3 ? (c2 ? i2 : n) : i3;
    d2 = c2 ? (c1 ? d1 : t) : d2;   i2 = c2 ? (c1 ? i1 : n) : i2;
    d1 = c1 ? (c0 ? d0 : t) : d1;   i1 = c1 ? (c0 ? i0 : n) : i1;
    d0 = c0 ? t : d0;               i0 = c0 ? n : i0;
}

// DEDUP variant: for ring re-merges where lists share phase-1 survivors.
__device__ __forceinline__ void lexins_d(float t, int n,
                                         float& d0, float& d1, float& d2, float& d3,
                                         int& i0, int& i1, int& i2, int& i3) {
    bool nd = !((n == i0) | (n == i1) | (n == i2) | (n == i3));
    bool c0 = nd && ((t < d0) || (t == d0 && n < i0));
    bool c1 = nd && ((t < d1) || (t == d1 && n < i1));
    bool c2 = nd && ((t < d2) || (t == d2 && n < i2));
    bool c3 = nd && ((t < d3) || (t == d3 && n < i3));
    d3 = c3 ? (c2 ? d2 : t) : d3;   i3 = c3 ? (c2 ? i2 : n) : i3;
    d2 = c2 ? (c1 ? d1 : t) : d2;   i2 = c2 ? (c1 ? i1 : n) : i2;
    d1 = c1 ? (c0 ? d0 : t) : d1;   i1 = c1 ? (c0 ? i0 : n) : i1;
    d0 = c0 ? t : d0;               i0 = c0 ? n : i0;
}

// strict-< variant for the ascending-order brute-force fallback
__device__ __forceinline__ void bins4(float t, int n,
                                      float& d0, float& d1, float& d2, float& d3,
                                      int& i0, int& i1, int& i2, int& i3) {
    bool c0 = t < d0, c1 = t < d1, c2 = t < d2, c3 = t < d3;
    d3 = c3 ? (c2 ? d2 : t) : d3;   i3 = c3 ? (c2 ? i2 : n) : i3;
    d2 = c2 ? (c1 ? d1 : t) : d2;   i2 = c2 ? (c1 ? i1 : n) : i2;
    d1 = c1 ? (c0 ? d0 : t) : d1;   i1 = c1 ? (c0 ? i0 : n) : i1;
    d0 = c0 ? t : d0;               i0 = c0 ? n : i0;
}

// ---------------------------------------------------------------------------
// Kernel FRONT (fused, 256 threads):
//  blocks [0, 1024):       off/attn projections, 2 rows/block (two 128-thread
//                          halves; per-(row,output) fmaf chain bitwise-
//                          identical to the validated 1-row version)
//  blocks [1024, 2048):    values = kv@W_v + b_v -> bf16 [b*H][n_kv][32]
//  blocks [2048, 2048+B):  kv binning into 16x16 cells
// ---------------------------------------------------------------------------
__global__ void k_front(const float* __restrict__ q, const float* __restrict__ qpos,
                        const float* __restrict__ Woff, const float* __restrict__ boff,
                        const float* __restrict__ Wattn, const float* __restrict__ battn,
                        const float* __restrict__ kv, const float* __restrict__ Wv,
                        const float* __restrict__ bv, const float* __restrict__ kvpos,
                        float* __restrict__ loc, float* __restrict__ attnw,
                        ushortb* __restrict__ vwsb,
                        float4* __restrict__ pts4, int* __restrict__ cellStart) {
    #pragma clang fp contract(off)
    if (blockIdx.x < (BATCH * NQ) / 2) {
        // ---- offattn: rows r0, r0+1 ----
        int r0 = blockIdx.x * 2;
        __shared__ float qs2[2][D];
        for (int t = threadIdx.x; t < 2 * D; t += 256) qs2[t >> 8][t & 255] = q[(size_t)r0 * D + t];
        __syncthreads();
        int half = threadIdx.x >> 7;             // 0 or 1
        int j = threadIdx.x & 127;
        int row = r0 + half;
        int b = row >> 10, qi = row & (NQ - 1);
        const float* qs = qs2[half];
        if (j < 64) {
            float acc = 0.0f;
            for (int d = 0; d < D; ++d) acc = fmaf(qs[d], Woff[d * 64 + j], acc);
            float off = acc + boff[j];           // bias after, like np
            int xy = j & 1;
            int hk = j >> 1;                     // h*4 + k
            int h = hk >> 2, k = hk & 3;
            float L = qpos[(size_t)row * 2 + xy] + off;
            int g = ((b * H + h) * NQ + qi) * K + k;
            loc[(size_t)g * 2 + xy] = L;
        } else if (j < 96) {
            int j2 = j - 64;                     // h*4 + k
            float acc = 0.0f;
            for (int d = 0; d < D; ++d) acc = fmaf(qs[d], Wattn[d * 32 + j2], acc);
            acc += battn[j2];
            float m = acc;
            m = fmaxf(m, __shfl_xor(m, 1));
            m = fmaxf(m, __shfl_xor(m, 2));
            float e = expf(acc - m);
            float s = e;
            s += __shfl_xor(s, 1);
            s += __shfl_xor(s, 2);
            float w = e / s;
            int h = j2 >> 2, k = j2 & 3;
            attnw[((b * H + h) * NQ + qi) * K + k] = w;
        }
        return;
    }
    if (blockIdx.x < (BATCH * NQ) / 2 + BATCH * NKV / 4) {
        // ---- values: 4 kv rows/block (R9-validated structure, bf16 store) ----
        int r0 = (blockIdx.x - (BATCH * NQ) / 2) * 4;
        __shared__ float ks[4][D];
        for (int t = threadIdx.x; t < 4 * D; t += 256) ks[t >> 8][t & 255] = kv[(size_t)r0 * D + t];
        __syncthreads();
        int c = threadIdx.x;                     // h*32 + cc
        float a0 = 0.f, a1 = 0.f, a2 = 0.f, a3 = 0.f;
        for (int d = 0; d < D; ++d) {
            float w = Wv[d * D + c];
            a0 = fmaf(ks[0][d], w, a0); a1 = fmaf(ks[1][d], w, a1);
            a2 = fmaf(ks[2][d], w, a2); a3 = fmaf(ks[3][d], w, a3);
        }
        float bias = bv[c];
        a0 += bias; a1 += bias; a2 += bias; a3 += bias;
        int h = c >> 5, cc = c & 31;
        float va[4] = {a0, a1, a2, a3};
        for (int r = 0; r < 4; ++r) {
            int row = r0 + r;
            int b = row >> 11, n = row & (NKV - 1);
            vwsb[(((size_t)(b * H + h) * NKV) + n) * CH + cc] = f2bf(va[r]);
        }
        return;
    }
    // ---- bin: one block per batch ----
    {
        int b = blockIdx.x - ((BATCH * NQ) / 2 + BATCH * NKV / 4);
        int tid = threadIdx.x;
        __shared__ int cnt[GC * GC];
        __shared__ int ofs[GC * GC + 1];
        __shared__ int cur[GC * GC];
        if (tid < GC * GC) cnt[tid] = 0;
        __syncthreads();
        for (int n = tid; n < NKV; n += 256) {
            float x = kvpos[(size_t)(b * NKV + n) * 2 + 0];
            float y = kvpos[(size_t)(b * NKV + n) * 2 + 1];
            int ix = min(GC - 1, max(0, (int)floorf(x * (float)GC)));
            int iy = min(GC - 1, max(0, (int)floorf(y * (float)GC)));
            atomicAdd(&cnt[iy * GC + ix], 1);
        }
        __syncthreads();
        if (tid == 0) {
            int s = 0;
            for (int c = 0; c < GC * GC; ++c) { ofs[c] = s; s += cnt[c]; }
            ofs[GC * GC] = s;
        }
        __syncthreads();
        for (int t = tid; t < GC * GC + 1; t += 256) cellStart[b * 257 + t] = ofs[t];
        if (tid < GC * GC) cur[tid] = ofs[tid];
        __syncthreads();
        for (int n = tid; n < NKV; n += 256) {
            float x = kvpos[(size_t)(b * NKV + n) * 2 + 0];
            float y = kvpos[(size_t)(b * NKV + n) * 2 + 1];
            int ix = min(GC - 1, max(0, (int)floorf(x * (float)GC)));
            int iy = min(GC - 1, max(0, (int)floorf(y * (float)GC)));
            int pos = atomicAdd(&cur[iy * GC + ix], 1);
            pts4[(size_t)b * NKV + pos] = make_float4(-2.0f * x, -2.0f * y, x * x + y * y, (float)n);
        }
    }
}

// ---------------------------------------------------------------------------
// Kernel 3 (R9-validated structure): grid 4-NN, 8 lanes/point, 3x3 box +
// ring, flattened rows + 4-wide batched loads, inline tail (bf16 gather).
// ---------------------------------------------------------------------------
__global__ void k_knn_grid2(const float* __restrict__ kvpos, const float* __restrict__ loc,
                            const float* __restrict__ attnw, const ushortb* __restrict__ vwsb,
                            const float* __restrict__ sp,
                            const float4* __restrict__ pts4, const int* __restrict__ cellStart,
                            float* __restrict__ head) {
    #pragma clang fp contract(off)
    int lane = threadIdx.x;
    int s = lane & 7;
    int g = blockIdx.x * 32 + (lane >> 3);    // point id
    int b = g >> 15;
    int bh = g >> 12;

    __shared__ int cst[GC * GC + 1];
    for (int i = threadIdx.x; i < GC * GC + 1; i += 256) cst[i] = cellStart[b * 257 + i];
    __syncthreads();

    const float4* gp = pts4 + (size_t)b * NKV;
    float2 L = ((const float2*)loc)[g];
    float lx = L.x, ly = L.y;
    float sl = lx * lx + ly * ly;

    int ix = min(GC - 1, max(0, (int)floorf(lx * (float)GC)));
    int iy = min(GC - 1, max(0, (int)floorf(ly * (float)GC)));

    float d0 = 1e30f, d1 = 1e30f, d2 = 1e30f, d3 = 1e30f;
    int i0 = 0x7FFFFFFF, i1 = 0x7FFFFFFF, i2 = 0x7FFFFFFF, i3 = 0x7FFFFFFF;

#define INS1(P) { float tt = (sl + (P).z) + fmaf(ly, (P).y, lx * (P).x);      \
                  lexins(tt, (int)(P).w, d0, d1, d2, d3, i0, i1, i2, i3); }

    // ---- phase 1: clamped 3x3 box, flattened rows, 4-wide batched loads ----
    {
        int bx0 = max(ix - 1, 0), bx1 = min(ix + 1, GC - 1);
        int by0 = max(iy - 1, 0), by1 = min(iy + 1, GC - 1);
        int a0 = cst[by0 * GC + bx0];
        int l0 = cst[by0 * GC + bx1 + 1] - a0;
        int a1 = 0, l1 = 0, a2 = 0, l2 = 0;
        if (by0 + 1 <= by1) { a1 = cst[(by0 + 1) * GC + bx0]; l1 = cst[(by0 + 1) * GC + bx1 + 1] - a1; }
        if (by0 + 2 <= by1) { a2 = cst[(by0 + 2) * GC + bx0]; l2 = cst[(by0 + 2) * GC + bx1 + 1] - a2; }
        int l01 = l0 + l1;
        int m = l01 + l2;
        int f = s;
        for (; f + 24 < m; f += 32) {
            int f0 = f, f1 = f + 8, f2 = f + 16, f3 = f + 24;
            int j0 = f0 < l0 ? a0 + f0 : (f0 < l01 ? a1 + (f0 - l0) : a2 + (f0 - l01));
            int j1 = f1 < l0 ? a0 + f1 : (f1 < l01 ? a1 + (f1 - l0) : a2 + (f1 - l01));
            int j2 = f2 < l0 ? a0 + f2 : (f2 < l01 ? a1 + (f2 - l0) : a2 + (f2 - l01));
            int j3 = f3 < l0 ? a0 + f3 : (f3 < l01 ? a1 + (f3 - l0) : a2 + (f3 - l01));
            float4 p0 = gp[j0], p1 = gp[j1], p2 = gp[j2], p3 = gp[j3];
            INS1(p0); INS1(p1); INS1(p2); INS1(p3);
        }
        for (; f < m; f += 8) {
            int j = f < l0 ? a0 + f : (f < l01 ? a1 + (f - l0) : a2 + (f - l01));
            float4 p = gp[j];
            INS1(p);
        }
    }

#define MERGE_P(M) {                                                           \
        float e0 = __shfl_xor(d0, M), e1 = __shfl_xor(d1, M);                  \
        float e2 = __shfl_xor(d2, M), e3 = __shfl_xor(d3, M);                  \
        int j0 = __shfl_xor(i0, M), j1 = __shfl_xor(i1, M);                    \
        int j2 = __shfl_xor(i2, M), j3 = __shfl_xor(i3, M);                    \
        lexins(e0, j0, d0, d1, d2, d3, i0, i1, i2, i3);                        \
        lexins(e1, j1, d0, d1, d2, d3, i0, i1, i2, i3);                        \
        lexins(e2, j2, d0, d1, d2, d3, i0, i1, i2, i3);                        \
        lexins(e3, j3, d0, d1, d2, d3, i0, i1, i2, i3);                        \
    }
#define MERGE_D(M) {                                                           \
        float e0 = __shfl_xor(d0, M), e1 = __shfl_xor(d1, M);                  \
        float e2 = __shfl_xor(d2, M), e3 = __shfl_xor(d3, M);                  \
        int j0 = __shfl_xor(i0, M), j1 = __shfl_xor(i1, M);                    \
        int j2 = __shfl_xor(i2, M), j3 = __shfl_xor(i3, M);                    \
        lexins_d(e0, j0, d0, d1, d2, d3, i0, i1, i2, i3);                      \
        lexins_d(e1, j1, d0, d1, d2, d3, i0, i1, i2, i3);                      \
        lexins_d(e2, j2, d0, d1, d2, d3, i0, i1, i2, i3);                      \
        lexins_d(e3, j3, d0, d1, d2, d3, i0, i1, i2, i3);                      \
    }

    MERGE_P(1);
    MERGE_P(2);
    MERGE_P(4);

    auto done_at = [&](int r) -> bool {
        int bx0 = ix - r, bx1 = ix + r, by0 = iy - r, by1 = iy + r;
        float bound = 1e30f;
        if (bx0 > 0)      bound = fminf(bound, lx - (float)bx0 * CELLH);
        if (bx1 < GC - 1) bound = fminf(bound, (float)(bx1 + 1) * CELLH - lx);
        if (by0 > 0)      bound = fminf(bound, ly - (float)by0 * CELLH);
        if (by1 < GC - 1) bound = fminf(bound, (float)(by1 + 1) * CELLH - ly);
        bool covered = (bx0 <= 0 && bx1 >= GC - 1 && by0 <= 0 && by1 >= GC - 1);
        return covered || (d3 < bound * bound - 1e-5f);
    };

#define SCAN_RANGE_S(JLO, JHI)                                       \
    for (int j = (JLO) + s; j < (JHI); j += 8) {                     \
        float4 p = gp[j];                                            \
        INS1(p);                                                     \
    }

    int r = 1;
    bool need = !done_at(1);
    while (__any(need)) {
        ++r;
        if (need) {
            int ry0 = iy - r, ry1 = iy + r;
            int rx0 = ix - r, rx1 = ix + r;
            int ca = max(rx0, 0), cb = min(rx1, GC - 1);
            if (ry0 >= 0)      { int base = ry0 * GC; SCAN_RANGE_S(cst[base + ca], cst[base + cb + 1]); }
            if (ry1 <= GC - 1) { int base = ry1 * GC; SCAN_RANGE_S(cst[base + ca], cst[base + cb + 1]); }
            int ya = max(ry0 + 1, 0), yb = min(ry1 - 1, GC - 1);
            if (rx0 >= 0)      for (int cy = ya; cy <= yb; ++cy) { int c = cy * GC + rx0; SCAN_RANGE_S(cst[c], cst[c + 1]); }
            if (rx1 <= GC - 1) for (int cy = ya; cy <= yb; ++cy) { int c = cy * GC + rx1; SCAN_RANGE_S(cst[c], cst[c + 1]); }
            MERGE_D(1);
            MERGE_D(2);
            MERGE_D(4);
            need = !done_at(r);
        }
    }
#undef SCAN_RANGE_S
#undef MERGE_P
#undef MERGE_D
#undef INS1

    // ---- tail, split 8-way over channel chunks (t = s), bf16 gather ----
    int bb = bh >> 3, h = bh & 7;
    int qi = (g >> 2) & (NQ - 1);
    float power = fmaxf(sp[0], 0.0f) + 1e-6f;
    int idx[4] = {i0, i1, i2, i3};
    float z[4];
    #pragma unroll
    for (int u = 0; u < 4; ++u) {
        float kx = kvpos[(size_t)(bb * NKV + idx[u]) * 2 + 0];
        float ky = kvpos[(size_t)(bb * NKV + idx[u]) * 2 + 1];
        float dx = kx - lx;
        float dy = ky - ly;
        float dist = sqrtf(dx * dx + dy * dy) + 1e-6f;
        z[u] = -power * dist;
    }
    float m = fmaxf(fmaxf(z[0], z[1]), fmaxf(z[2], z[3]));
    float e0 = expf(z[0] - m), e1 = expf(z[1] - m), e2 = expf(z[2] - m), e3 = expf(z[3] - m);
    float esum = e0 + e1 + e2 + e3;
    float w0 = e0 / esum, w1 = e1 / esum, w2 = e2 / esum, w3 = e3 / esum;

    const ushort4* vp0 = (const ushort4*)(vwsb + ((size_t)bh * NKV + i0) * CH);
    const ushort4* vp1 = (const ushort4*)(vwsb + ((size_t)bh * NKV + i1) * CH);
    const ushort4* vp2 = (const ushort4*)(vwsb + ((size_t)bh * NKV + i2) * CH);
    const ushort4* vp3 = (const ushort4*)(vwsb + ((size_t)bh * NKV + i3) * CH);
    float a = attnw[g];
    float4* hp = (float4*)(head + ((size_t)(bb * NQ + qi)) * D + h * CH);
    {
        ushort4 u0 = vp0[s], u1 = vp1[s], u2 = vp2[s], u3 = vp3[s];
        float4 rr;
        rr.x = a * (w0 * bf2f(u0.x) + w1 * bf2f(u1.x) + w2 * bf2f(u2.x) + w3 * bf2f(u3.x));
        rr.y = a * (w0 * bf2f(u0.y) + w1 * bf2f(u1.y) + w2 * bf2f(u2.y) + w3 * bf2f(u3.y));
        rr.z = a * (w0 * bf2f(u0.z) + w1 * bf2f(u1.z) + w2 * bf2f(u2.z) + w3 * bf2f(u3.z));
        rr.w = a * (w0 * bf2f(u0.w) + w1 * bf2f(u1.w) + w2 * bf2f(u2.w) + w3 * bf2f(u3.w));
        rr.x += __shfl_xor(rr.x, 8); rr.x += __shfl_xor(rr.x, 16);  // sum over k
        rr.y += __shfl_xor(rr.y, 8); rr.y += __shfl_xor(rr.y, 16);
        rr.z += __shfl_xor(rr.z, 8); rr.z += __shfl_xor(rr.z, 16);
        rr.w += __shfl_xor(rr.w, 8); rr.w += __shfl_xor(rr.w, 16);
        if (((lane >> 3) & 3) == 0) hp[s] = rr;                     // k==0 lanes write
    }
}

// Fallback (ws too small): brute-force fused scan (round-4 validated path,
// bf16 value gather).  Requires loc/attnw/vwsb already computed by k_front.
__global__ void k_knn_fused(const float* __restrict__ kvpos, const float* __restrict__ loc,
                            const float* __restrict__ attnw, const ushortb* __restrict__ vwsb,
                            const float* __restrict__ sp, float* __restrict__ head) {
    #pragma clang fp contract(off)
    int g = blockIdx.x * 256 + threadIdx.x;
    int bh = g >> 12;
    int b = bh >> 3;
    __shared__ float sx[NKV];
    __shared__ float sy[NKV];
    __shared__ float sz[NKV];
    for (int n = threadIdx.x; n < NKV; n += 256) {
        float x = kvpos[(size_t)(b * NKV + n) * 2 + 0];
        float y = kvpos[(size_t)(b * NKV + n) * 2 + 1];
        sx[n] = -2.0f * x;
        sy[n] = -2.0f * y;
        sz[n] = x * x + y * y;
    }
    __syncthreads();
    float2 L = ((const float2*)loc)[g];
    float lx = L.x, ly = L.y;
    float sl = lx * lx + ly * ly;
    const float4* x4 = (const float4*)sx;
    const float4* y4 = (const float4*)sy;
    const float4* z4 = (const float4*)sz;
    float d0 = 1e30f, d1 = 1e30f, d2 = 1e30f, d3 = 1e30f;
    int i0 = 0, i1 = 0, i2 = 0, i3 = 0;
    for (int n = 0; n < NKV; n += 4) {
        int v = n >> 2;
        float4 xA = x4[v], yA = y4[v], zA = z4[v];
        float t0 = (sl + zA.x) + fmaf(ly, yA.x, lx * xA.x);
        float t1 = (sl + zA.y) + fmaf(ly, yA.y, lx * xA.y);
        float t2 = (sl + zA.z) + fmaf(ly, yA.z, lx * xA.z);
        float t3 = (sl + zA.w) + fmaf(ly, yA.w, lx * xA.w);
        bins4(t0, n + 0, d0, d1, d2, d3, i0, i1, i2, i3);
        bins4(t1, n + 1, d0, d1, d2, d3, i0, i1, i2, i3);
        bins4(t2, n + 2, d0, d1, d2, d3, i0, i1, i2, i3);
        bins4(t3, n + 3, d0, d1, d2, d3, i0, i1, i2, i3);
    }
    float power = fmaxf(sp[0], 0.0f) + 1e-6f;
    int h = bh & 7;
    int qi = (g >> 2) & (NQ - 1);
    int k = g & 3;
    int idx[4] = {i0, i1, i2, i3};
    float z[4];
    #pragma unroll
    for (int u = 0; u < 4; ++u) {
        float kx = kvpos[(size_t)(b * NKV + idx[u]) * 2 + 0];
        float ky = kvpos[(size_t)(b * NKV + idx[u]) * 2 + 1];
        float dx = kx - lx;
        float dy = ky - ly;
        float dist = sqrtf(dx * dx + dy * dy) + 1e-6f;
        z[u] = -power * dist;
    }
    float m = fmaxf(fmaxf(z[0], z[1]), fmaxf(z[2], z[3]));
    float e0 = expf(z[0] - m), e1 = expf(z[1] - m), e2 = expf(z[2] - m), e3 = expf(z[3] - m);
    float esum = e0 + e1 + e2 + e3;
    float w0 = e0 / esum, w1 = e1 / esum, w2 = e2 / esum, w3 = e3 / esum;
    const ushort4* vp0 = (const ushort4*)(vwsb + ((size_t)bh * NKV + i0) * CH);
    const ushort4* vp1 = (const ushort4*)(vwsb + ((size_t)bh * NKV + i1) * CH);
    const ushort4* vp2 = (const ushort4*)(vwsb + ((size_t)bh * NKV + i2) * CH);
    const ushort4* vp3 = (const ushort4*)(vwsb + ((size_t)bh * NKV + i3) * CH);
    float a = attnw[g];
    float4 acc[8];
    #pragma unroll
    for (int t = 0; t < 8; ++t) {
        ushort4 u0 = vp0[t], u1 = vp1[t], u2 = vp2[t], u3 = vp3[t];
        float4 r;
        r.x = a * (w0 * bf2f(u0.x) + w1 * bf2f(u1.x) + w2 * bf2f(u2.x) + w3 * bf2f(u3.x));
        r.y = a * (w0 * bf2f(u0.y) + w1 * bf2f(u1.y) + w2 * bf2f(u2.y) + w3 * bf2f(u3.y));
        r.z = a * (w0 * bf2f(u0.z) + w1 * bf2f(u1.z) + w2 * bf2f(u2.z) + w3 * bf2f(u3.z));
        r.w = a * (w0 * bf2f(u0.w) + w1 * bf2f(u1.w) + w2 * bf2f(u2.w) + w3 * bf2f(u3.w));
        r.x += __shfl_xor(r.x, 1); r.x += __shfl_xor(r.x, 2);
        r.y += __shfl_xor(r.y, 1); r.y += __shfl_xor(r.y, 2);
        r.z += __shfl_xor(r.z, 1); r.z += __shfl_xor(r.z, 2);
        r.w += __shfl_xor(r.w, 1); r.w += __shfl_xor(r.w, 2);
        acc[t] = r;
    }
    float4* hp = (float4*)(head + ((size_t)(b * NQ + qi)) * D + h * CH);
    hp[k * 2]     = acc[k * 2];
    hp[k * 2 + 1] = acc[k * 2 + 1];
}

// ---------------------------------------------------------------------------
// Kernel 4: out = head @ W_out + b_out  (f32 store; R9 version, 4 rows/block)
// ---------------------------------------------------------------------------
__global__ void k_out(const float* __restrict__ head, const float* __restrict__ Wout,
                      const float* __restrict__ bout, float* __restrict__ out) {
    int r0 = blockIdx.x * 4;
    __shared__ float hs[4][D];
    for (int t = threadIdx.x; t < 4 * D; t += 256) hs[t >> 8][t & 255] = head[(size_t)r0 * D + t];
    __syncthreads();
    int c = threadIdx.x;
    float a0 = 0.f, a1 = 0.f, a2 = 0.f, a3 = 0.f;
    for (int d = 0; d < D; ++d) {
        float w = Wout[d * D + c];
        a0 = fmaf(hs[0][d], w, a0); a1 = fmaf(hs[1][d], w, a1);
        a2 = fmaf(hs[2][d], w, a2); a3 = fmaf(hs[3][d], w, a3);
    }
    float bias = bout[c];
    out[(size_t)(r0 + 0) * D + c] = a0 + bias;
    out[(size_t)(r0 + 1) * D + c] = a1 + bias;
    out[(size_t)(r0 + 2) * D + c] = a2 + bias;
    out[(size_t)(r0 + 3) * D + c] = a3 + bias;
}

// ---------------------------------------------------------------------------
extern "C" void kernel_launch(void* const* d_in, const int* in_sizes, int n_in,
                              void* d_out, int out_size, void* d_ws, size_t ws_size,
                              hipStream_t stream) {
    (void)in_sizes; (void)n_in; (void)out_size;
    const float* q     = (const float*)d_in[0];
    const float* qpos  = (const float*)d_in[1];
    const float* kv    = (const float*)d_in[2];
    const float* kvp   = (const float*)d_in[3];
    const float* Woff  = (const float*)d_in[4];
    const float* boff  = (const float*)d_in[5];
    const float* Wattn = (const float*)d_in[6];
    const float* battn = (const float*)d_in[7];
    const float* Wv    = (const float*)d_in[8];
    const float* bv    = (const float*)d_in[9];
    const float* Wout  = (const float*)d_in[10];
    const float* bout  = (const float*)d_in[11];
    const float* sp    = (const float*)d_in[12];
    float* out = (float*)d_out;

    char* ws = (char*)d_ws;
    float* loc      = (float*)(ws + OFF_LOC);
    float* attnw    = (float*)(ws + OFF_ATTN);
    ushortb* vwsb   = (ushortb*)(ws + OFF_VWS);
    float* head     = (float*)(ws + OFF_HEAD);
    float4* pts4    = (float4*)(ws + OFF_PTS);
    int* cellStart  = (int*)(ws + OFF_CST);

    bool grid_ok = ws_size >= (size_t)WS_NEED;
    int nfront = (BATCH * NQ) / 2 + BATCH * NKV / 4 + (grid_ok ? BATCH : 0);
    hipLaunchKernelGGL(k_front, dim3(nfront), dim3(256), 0, stream,
                       q, qpos, Woff, boff, Wattn, battn, kv, Wv, bv, kvp,
                       loc, attnw, vwsb, pts4, cellStart);
    if (grid_ok) {
        hipLaunchKernelGGL(k_knn_grid2, dim3(BATCH * H * NQ * K / 32), dim3(256), 0, stream,
                           kvp, loc, attnw, vwsb, sp, pts4, cellStart, head);
    } else {
        hipLaunchKernelGGL(k_knn_fused, dim3(BATCH * H * NQ * K / 256), dim3(256), 0, stream,
                           kvp, loc, attnw, vwsb, sp, head);
    }
    hipLaunchKernelGGL(k_out, dim3(BATCH * NQ / 4), dim3(256), 0, stream,
                       head, Wout, bout, out);
}